// Round 2
// baseline (11524.290 us; speedup 1.0000x reference)
//
#include <hip/hip_runtime.h>

typedef unsigned short u16;
typedef short short8 __attribute__((ext_vector_type(8)));
typedef float floatx4 __attribute__((ext_vector_type(4)));

static constexpr int CB = 16, CT = 256, CMEL = 1024, CD = 512, CH = 8, CDH = 64, CL = 4;
static constexpr int CINTER = 2048, COUT = 80;
static constexpr int CQKV = 3 * CH * CDH;   // 1536

static __device__ __forceinline__ float bf2f(u16 u) {
  union { unsigned u; float f; } v; v.u = ((unsigned)u) << 16; return v.f;
}
static __device__ __forceinline__ u16 f2bf(float f) {  // RNE; inputs are finite
  union { float f; unsigned u; } v; v.f = f;
  unsigned r = v.u + 0x7fffu + ((v.u >> 16) & 1u);
  return (u16)(r >> 16);
}

// ---------------------------------------------------------------------------
// Generic bf16 MFMA GEMM.
//   C[m,n] = alpha * sum_tap sum_k A[m + (tap-dtap), k] * B_tap[k, n]  (+bias, relu)
// TRB=true : B given as B^T (N x K rows) -- used for Q@K^T. N must be mult of BN.
// TRB=false: B given as K x N rows, staged transposed through LDS. N arbitrary.
// Taps (ntaps=3, dtap=1) implement SAME-padded conv1d; row validity via s in [0,Sseq).
// Batched via blockIdx.z: offsets (z/zH)*s?1 + (z%zH)*s?2.
// MFMA 16x16x32 bf16 frag maps (m89/m91-verified): A/B lane holds
// [idx=lane&15][k=(lane>>4)*8+j]; C/D col=lane&15, row=(lane>>4)*4+reg.
// ---------------------------------------------------------------------------
template<int BM, int BN, bool TRB, bool RELU, bool OUTF32>
__global__ __launch_bounds__(256)
void gemm_k(const u16* __restrict__ A, const u16* __restrict__ Bm,
            void* __restrict__ Cm, const float* __restrict__ bias,
            int M, int N, int K, int lda, int ldb, int ldc,
            float alpha, int Sseq, int ntaps, int dtap, long tapStrideB,
            int zH, long sA1, long sA2, long sB1, long sB2, long sC1, long sC2)
{
  constexpr int LDT = 40;  // 32 + 8 pad (16B-aligned rows, only free 2-way conflicts)
  __shared__ u16 As[BM * LDT];
  __shared__ u16 Bs[BN * LDT];

  const int t = threadIdx.x;
  const int lane = t & 63;
  const int wave = t >> 6;
  constexpr int WCOLS = BN / 64;
  const int wrow = wave / WCOLS;
  const int wcol = wave % WCOLS;
  const int bn0 = blockIdx.x * BN;
  const int bm0 = blockIdx.y * BM;
  const int z = blockIdx.z;
  const long offA = (long)(z / zH) * sA1 + (long)(z % zH) * sA2;
  const long offB = (long)(z / zH) * sB1 + (long)(z % zH) * sB2;
  const long offC = (long)(z / zH) * sC1 + (long)(z % zH) * sC2;

  floatx4 acc[4][4];
#pragma unroll
  for (int i = 0; i < 4; ++i)
#pragma unroll
    for (int j = 0; j < 4; ++j) acc[i][j] = (floatx4){0.f, 0.f, 0.f, 0.f};

  constexpr int APASS = BM / 64;
  int aRow[APASS], aKc[APASS], aS[APASS];
#pragma unroll
  for (int p = 0; p < APASS; ++p) {
    int lin = p * 256 + t;
    aRow[p] = lin >> 2;
    aKc[p]  = (lin & 3) << 3;
    aS[p]   = (bm0 + aRow[p]) % Sseq;
  }

  for (int tap = 0; tap < ntaps; ++tap) {
    const int dlt = tap - dtap;
    for (int k0 = 0; k0 < K; k0 += 32) {
      // ---- stage A tile (BM x 32)
#pragma unroll
      for (int p = 0; p < APASS; ++p) {
        uint4 v = make_uint4(0u, 0u, 0u, 0u);
        if ((unsigned)(aS[p] + dlt) < (unsigned)Sseq) {
          const u16* src = A + offA + (long)(bm0 + aRow[p] + dlt) * lda + (k0 + aKc[p]);
          v = *(const uint4*)src;
        }
        *(uint4*)&As[aRow[p] * LDT + aKc[p]] = v;
      }
      // ---- stage B tile ([n][k] in LDS)
      if (TRB) {
#pragma unroll
        for (int p = 0; p < BN / 64; ++p) {
          int lin = p * 256 + t;
          int row = lin >> 2;
          int kc  = (lin & 3) << 3;
          const u16* src = Bm + offB + (long)(bn0 + row) * ldb + (k0 + kc);
          *(uint4*)&Bs[row * LDT + kc] = *(const uint4*)src;
        }
      } else {
#pragma unroll
        for (int p = 0; p < BN / 16; ++p) {
          int lin = p * 256 + t;
          int kk = lin / (BN / 2);
          int nn = (lin - kk * (BN / 2)) * 2;
          int gn = bn0 + nn;
          u16 b0 = 0, b1 = 0;
          const u16* bp = Bm + offB + tap * tapStrideB + (long)(k0 + kk) * ldb + gn;
          if (gn + 1 < N) { unsigned u = *(const unsigned*)bp; b0 = (u16)u; b1 = (u16)(u >> 16); }
          else if (gn < N) { b0 = bp[0]; }
          Bs[nn * LDT + kk] = b0;
          Bs[(nn + 1) * LDT + kk] = b1;
        }
      }
      __syncthreads();

      short8 af[4], bfr[4];
      const int fk = (lane >> 4) << 3;
      const int fm = lane & 15;
#pragma unroll
      for (int i = 0; i < 4; ++i)
        af[i] = *(const short8*)&As[(wrow * 64 + i * 16 + fm) * LDT + fk];
#pragma unroll
      for (int j = 0; j < 4; ++j)
        bfr[j] = *(const short8*)&Bs[(wcol * 64 + j * 16 + fm) * LDT + fk];
#pragma unroll
      for (int i = 0; i < 4; ++i)
#pragma unroll
        for (int j = 0; j < 4; ++j)
          acc[i][j] = __builtin_amdgcn_mfma_f32_16x16x32_bf16(af[i], bfr[j], acc[i][j], 0, 0, 0);
      __syncthreads();
    }
  }

  const int rbase = bm0 + wrow * 64 + ((lane >> 4) << 2);
  const int cbase = bn0 + wcol * 64 + (lane & 15);
#pragma unroll
  for (int j = 0; j < 4; ++j) {
    int col = cbase + j * 16;
    if (col >= N) continue;
    float bv = bias ? bias[col] : 0.f;
#pragma unroll
    for (int i = 0; i < 4; ++i) {
#pragma unroll
      for (int r = 0; r < 4; ++r) {
        int row = rbase + i * 16 + r;
        float v = acc[i][j][r] * alpha + bv;
        if (RELU) v = fmaxf(v, 0.f);
        long ci = offC + (long)row * ldc + col;
        if (OUTF32) ((float*)Cm)[ci] = v;
        else        ((u16*)Cm)[ci] = f2bf(v);
      }
    }
  }
}

template<int BM, int BN, bool TRB, bool RELU, bool OUTF32>
static inline void launch_gemm(hipStream_t st, const u16* A, const u16* B, void* C,
                               const float* bias, int M, int N, int K,
                               int lda, int ldb, int ldc, float alpha,
                               int Sseq, int ntaps, int dtap, long tapB,
                               int Z = 1, int zH = 1,
                               long sA1 = 0, long sA2 = 0, long sB1 = 0, long sB2 = 0,
                               long sC1 = 0, long sC2 = 0)
{
  dim3 grid((unsigned)((N + BN - 1) / BN), (unsigned)(M / BM), (unsigned)Z);
  gemm_k<BM, BN, TRB, RELU, OUTF32><<<grid, dim3(256), 0, st>>>(
      A, B, C, bias, M, N, K, lda, ldb, ldc, alpha, Sseq, ntaps, dtap, tapB,
      zH, sA1, sA2, sB1, sB2, sC1, sC2);
}

// ---------------------------------------------------------------------------
__global__ void cvt_k(const float* __restrict__ s, u16* __restrict__ d, long n)
{
  long i = (long)blockIdx.x * 256 + threadIdx.x;
  if (i < n) d[i] = f2bf(s[i]);
}

__global__ void fill_k(float* __restrict__ o, int n, float v)
{
  int i = blockIdx.x * 256 + threadIdx.x;
  if (i < n) o[i] = v;
}

// x[b,t,:] = bf16( 2*emb[tok] + pos[b] )   (reference quirk: pos indexed by BATCH b)
__global__ void embed_k(const int* __restrict__ tok, const float* __restrict__ emb,
                        u16* __restrict__ X)
{
  const long idx = (long)blockIdx.x * 256 + threadIdx.x;  // < B*T*D
  const int d = (int)(idx & (CD - 1));
  const int m = (int)(idx >> 9);
  const int b = m >> 8;  // T = 256
  const float e = emb[(long)tok[m] * CD + d];
  const int i2 = d >> 1;
  const float den = __expf(-(float)(2 * i2) * (9.210340371976184f / 512.f));
  const float ang = (float)b * den;
  const float p = (d & 1) ? __cosf(ang) : __sinf(ang);
  X[idx] = f2bf(2.f * e + p);
}

// masked softmax over last dim, in place, bf16. grid (S, Z); b = z/zH
__global__ void softmax_k(u16* __restrict__ Sc, const int* __restrict__ lens, int S, int zH)
{
  const int q = blockIdx.x, z = blockIdx.y, t = threadIdx.x;
  const int len = lens[z / zH];
  u16* row = Sc + ((long)z * S + q) * S;
  const int nv = S >> 8;  // 1 (enc) or 4 (dec)
  float vals[4];
  float mx = -1e30f;
  for (int i = 0; i < nv; ++i) {
    int k = t + (i << 8);
    float v = (k <= len) ? bf2f(row[k]) : -1e30f;
    vals[i] = v; mx = fmaxf(mx, v);
  }
  __shared__ float red[256];
  red[t] = mx; __syncthreads();
  for (int s = 128; s > 0; s >>= 1) { if (t < s) red[t] = fmaxf(red[t], red[t + s]); __syncthreads(); }
  mx = red[0]; __syncthreads();
  float sum = 0.f;
  for (int i = 0; i < nv; ++i) { float e = __expf(vals[i] - mx); vals[i] = e; sum += e; }
  red[t] = sum; __syncthreads();
  for (int s = 128; s > 0; s >>= 1) { if (t < s) red[t] += red[t + s]; __syncthreads(); }
  const float inv = 1.f / red[0];
  for (int i = 0; i < nv; ++i) row[t + (i << 8)] = f2bf(vals[i] * inv);
}

// O = LN(X + Y) * g + b ; one block per row, D=512, f32 stats
__global__ void ln_res_k(const u16* __restrict__ X, const u16* __restrict__ Y,
                         const float* __restrict__ g, const float* __restrict__ bta,
                         u16* __restrict__ O)
{
  const int m = blockIdx.x, t = threadIdx.x;
  const long base = (long)m * CD;
  float v0 = bf2f(X[base + t]) + bf2f(Y[base + t]);
  float v1 = bf2f(X[base + t + 256]) + bf2f(Y[base + t + 256]);
  __shared__ float red[256];
  red[t] = v0 + v1; __syncthreads();
  for (int s = 128; s > 0; s >>= 1) { if (t < s) red[t] += red[t + s]; __syncthreads(); }
  const float mean = red[0] * (1.f / 512.f);
  __syncthreads();
  const float d0 = v0 - mean, d1 = v1 - mean;
  red[t] = d0 * d0 + d1 * d1; __syncthreads();
  for (int s = 128; s > 0; s >>= 1) { if (t < s) red[t] += red[t + s]; __syncthreads(); }
  const float rstd = rsqrtf(red[0] * (1.f / 512.f) + 1e-5f);
  O[base + t]       = f2bf(d0 * rstd * g[t] + bta[t]);
  O[base + t + 256] = f2bf(d1 * rstd * g[t + 256] + bta[t + 256]);
}

__global__ void cumsum_k(const int* __restrict__ dur, int* __restrict__ cums)
{
  int b = threadIdx.x;
  if (b < CB) {
    int s = 0;
    for (int t = 0; t < CT; ++t) { s += dur[b * CT + t]; cums[b * CT + t] = s; }
  }
}

// dec_in[b,f,:] = keep * enc[b, searchsorted_right(cums[b], f) (clipped), :]
__global__ void regulate_k(const u16* __restrict__ xe, const int* __restrict__ cums,
                           const int* __restrict__ mlen, u16* __restrict__ xd)
{
  const int m = blockIdx.x;      // b*MEL + f
  const int b = m >> 10, f = m & (CMEL - 1);
  int lo = 0, hi = CT;
  while (lo < hi) { int mid = (lo + hi) >> 1; if (cums[b * CT + mid] <= f) lo = mid + 1; else hi = mid; }
  const int idx = min(lo, CT - 1);
  const bool keep = (f <= mlen[b]);
  const u16* src = xe + ((long)b * CT + idx) * CD;
  u16* dst = xd + (long)m * CD;
  const int t = threadIdx.x;
  dst[t]       = keep ? src[t] : (u16)0;
  dst[t + 256] = keep ? src[t + 256] : (u16)0;
}

// out[b,o,f] = tmp[b*MEL+f, o]
__global__ void outtr_k(const float* __restrict__ tmp, float* __restrict__ out)
{
  const int i = blockIdx.x * 256 + threadIdx.x;   // < B*OUT*MEL
  const int f = i & (CMEL - 1);
  const int bo = i >> 10;
  const int o = bo % COUT;
  const int b = bo / COUT;
  out[i] = tmp[((long)b * CMEL + f) * COUT + o];
}

// ---------------------------------------------------------------------------
extern "C" void kernel_launch(void* const* d_in, const int* in_sizes, int n_in,
                              void* d_out, int out_size, void* d_ws, size_t ws_size,
                              hipStream_t stream)
{
  (void)in_sizes; (void)n_in;
  const int*   tokens = (const int*)d_in[0];
  const int*   tlen   = (const int*)d_in[1];
  const int*   mlen   = (const int*)d_in[2];
  const int*   dur    = (const int*)d_in[3];
  const float* emb    = (const float*)d_in[5];
  const float* ew[12]; const float* dw[12];
  for (int i = 0; i < 12; ++i) { ew[i] = (const float*)d_in[6 + i]; dw[i] = (const float*)d_in[18 + i]; }
  const float* out_w = (const float*)d_in[30];
  const float* out_b = (const float*)d_in[31];
  // stack weight idx: 0 wqkv,1 bqkv,2 wo,3 bo,4 ln1g,5 ln1b,6 c1w,7 c1b,8 c2w,9 c2b,10 ln2g,11 ln2b

  const int Me = CB * CT;       // 4096
  const int Md = CB * CMEL;     // 16384

  // ---- workspace layout with lifetime aliasing ------------------------------
  const size_t SZ_WBUF = (size_t)3 * CD * CINTER * 2;        // 6.3 MB (max per-GEMM weight)
  const size_t SZ_XE   = (size_t)Me * CD * 2;                // 4.2 MB
  const size_t SZ_XD   = (size_t)Md * CD * 2;                // 16.8 MB (x, x1, yb)
  const size_t SZ_QKV  = (size_t)Md * CQKV * 2;              // 50.3 MB
  const size_t SZ_HB   = (size_t)Md * CINTER * 2;            // 67.1 MB
  const size_t SZ_FT   = (size_t)Md * COUT * 4;              // 5.2 MB
  const size_t SZ_CUMS = (size_t)CB * CT * 4;
  auto al = [](size_t b) { return (b + 255) & ~(size_t)255; };

  auto totalFor = [&](int hch) -> size_t {
    size_t sc = (size_t)CB * hch * CMEL * CMEL * 2;
    size_t U = al(SZ_QKV) + al(sc);
    if (al(SZ_HB) > U) U = al(SZ_HB);
    if (al(SZ_FT) > U) U = al(SZ_FT);
    return al(SZ_WBUF) + al(SZ_XE) + 3 * al(SZ_XD) + U + al(SZ_CUMS);
  };
  int HCHv = 0;
  for (int h : {8, 4, 2, 1}) { if (totalFor(h) <= ws_size) { HCHv = h; break; } }
  if (HCHv == 0) {  // sentinel: absmax ~1000 => ws_size too small (distinguishable)
    fill_k<<<dim3((unsigned)((out_size + 255) / 256)), dim3(256), 0, stream>>>(
        (float*)d_out, out_size, 1000.0f);
    return;
  }

  char* p = (char*)d_ws;
  auto take = [&](size_t bytes) { char* r = p; p += al(bytes); return r; };
  u16*  wbuf = (u16*)take(SZ_WBUF);
  u16*  xe   = (u16*)take(SZ_XE);
  u16*  xd   = (u16*)take(SZ_XD);
  u16*  x1   = (u16*)take(SZ_XD);
  u16*  yb   = (u16*)take(SZ_XD);
  char* U0   = take(0);            // union region start
  u16*  qkvB = (u16*)U0;
  u16*  sc   = (u16*)(U0 + al(SZ_QKV));
  u16*  hb   = (u16*)U0;
  float* ftmp = (float*)U0;
  {
    size_t sc_sz = (size_t)CB * HCHv * CMEL * CMEL * 2;
    size_t U = al(SZ_QKV) + al(sc_sz);
    if (al(SZ_HB) > U) U = al(SZ_HB);
    if (al(SZ_FT) > U) U = al(SZ_FT);
    (void)take(U);
  }
  int* cums = (int*)take(SZ_CUMS);

  auto cvt = [&](const float* s, u16* d, long n) {
    cvt_k<<<dim3((unsigned)((n + 255) / 256)), dim3(256), 0, stream>>>(s, d, n);
  };

  embed_k<<<dim3((unsigned)((long)Me * CD / 256)), dim3(256), 0, stream>>>(tokens, emb, xe);

  auto run_stack = [&](u16* x, int S, int M, const int* lens, const float* const* W) {
    for (int l = 0; l < CL; ++l) {
      // qkv = x @ Wqkv + b
      cvt(W[0] + (long)l * CD * CQKV, wbuf, (long)CD * CQKV);
      launch_gemm<128, 128, false, false, false>(stream, x, wbuf, qkvB, W[1] + l * CQKV,
          M, CQKV, CD, CD, CQKV, CQKV, 1.f, M, 1, 0, 0);
      // attention, HCHv heads per chunk; PV result overwrites consumed Q slice
      for (int c = 0; c < CH / HCHv; ++c) {
        const int h0 = c * HCHv;
        const int Z = CB * HCHv;
        launch_gemm<128, 128, true, false, false>(stream,
            qkvB + h0 * CDH, qkvB + CD + h0 * CDH, sc, nullptr,
            S, S, CDH, CQKV, CQKV, S, 0.125f, S, 1, 0, 0,
            Z, HCHv, (long)S * CQKV, CDH, (long)S * CQKV, CDH,
            (long)HCHv * S * S, (long)S * S);
        softmax_k<<<dim3((unsigned)S, (unsigned)Z), dim3(256), 0, stream>>>(sc, lens, S, HCHv);
        launch_gemm<256, 64, false, false, false>(stream,
            sc, qkvB + 2 * CD + h0 * CDH, qkvB + h0 * CDH, nullptr,
            S, CDH, S, S, CQKV, CQKV, 1.f, S, 1, 0, 0,
            Z, HCHv, (long)HCHv * S * S, (long)S * S, (long)S * CQKV, CDH,
            (long)S * CQKV, CDH);
      }
      // proj: ctx (= qkvB cols 0..511) @ Wo + bo
      cvt(W[2] + (long)l * CD * CD, wbuf, (long)CD * CD);
      launch_gemm<128, 128, false, false, false>(stream, qkvB, wbuf, yb, W[3] + l * CD,
          M, CD, CD, CQKV, CD, CD, 1.f, M, 1, 0, 0);
      ln_res_k<<<dim3((unsigned)M), dim3(256), 0, stream>>>(x, yb, W[4] + l * CD, W[5] + l * CD, x1);
      // conv1 (3-tap) + relu
      cvt(W[6] + (long)l * 3 * CD * CINTER, wbuf, (long)3 * CD * CINTER);
      launch_gemm<128, 128, false, true, false>(stream, x1, wbuf, hb, W[7] + l * CINTER,
          M, CINTER, CD, CD, CINTER, CINTER, 1.f, S, 3, 1, (long)CD * CINTER);
      // conv2 (3-tap)
      cvt(W[8] + (long)l * 3 * CINTER * CD, wbuf, (long)3 * CINTER * CD);
      launch_gemm<128, 128, false, false, false>(stream, hb, wbuf, yb, W[9] + l * CD,
          M, CD, CINTER, CINTER, CD, CD, 1.f, S, 3, 1, (long)CINTER * CD);
      ln_res_k<<<dim3((unsigned)M), dim3(256), 0, stream>>>(x1, yb, W[10] + l * CD, W[11] + l * CD, x);
    }
  };

  run_stack(xe, CT, Me, tlen, ew);

  cumsum_k<<<dim3(1), dim3(64), 0, stream>>>(dur, cums);
  regulate_k<<<dim3((unsigned)(CB * CMEL)), dim3(256), 0, stream>>>(xe, cums, mlen, xd);

  run_stack(xd, CMEL, Md, mlen, dw);

  // final projection + transpose
  cvt(out_w, wbuf, (long)CD * COUT);
  launch_gemm<128, 128, false, false, true>(stream, xd, wbuf, ftmp, out_b,
      Md, COUT, CD, CD, COUT, COUT, 1.f, Md, 1, 0, 0);
  outtr_k<<<dim3((unsigned)(CB * COUT * CMEL / 256)), dim3(256), 0, stream>>>(ftmp, (float*)d_out);
}

// Round 3
// 4704.861 us; speedup vs baseline: 2.4494x; 2.4494x over previous
//
#include <hip/hip_runtime.h>

typedef unsigned short u16;
typedef short short8 __attribute__((ext_vector_type(8)));
typedef float floatx4 __attribute__((ext_vector_type(4)));

static constexpr int CB = 16, CT = 256, CMEL = 1024, CD = 512, CH = 8, CDH = 64, CL = 4;
static constexpr int CINTER = 2048, COUT = 80;
static constexpr int CQKV = 3 * CH * CDH;   // 1536

static __device__ __forceinline__ float bf2f(u16 u) {
  union { unsigned u; float f; } v; v.u = ((unsigned)u) << 16; return v.f;
}
static __device__ __forceinline__ u16 f2bf(float f) {  // RNE; inputs finite
  union { float f; unsigned u; } v; v.f = f;
  unsigned r = v.u + 0x7fffu + ((v.u >> 16) & 1u);
  return (u16)(r >> 16);
}

// async global->LDS, 16B per lane; LDS dest = wave-uniform base + lane*16 (m104/m108)
static __device__ __forceinline__ void gld16(const u16* g, u16* lds) {
  __builtin_amdgcn_global_load_lds((const __attribute__((address_space(1))) void*)g,
                                   (__attribute__((address_space(3))) void*)lds, 16, 0, 0);
}

// ---------------------------------------------------------------------------
// Unified bf16 MFMA GEMM. Both operands are row-major K-contiguous (A: M x K,
// B: N x K, i.e. weights pre-transposed). Staged via global_load_lds dwordx4.
// LDS layout: row r = 32 u16 (64B) = 4 granules of 16B; granule g stored at
// slot g ^ ((r>>1)&3)  -> fragment ds_read_b128 hits 8 bank-groups 2-way (free).
// The swizzle is realized in the GLOBAL address each lane loads:
//   lane i of a 16-row wave pass: r = R0 + (i>>2), loads granule (i&3)^((i>>3)&3).
// Conv taps (ntaps=3, dtap=1): A row shifted by tap-dtap, validity via seq pos;
// invalid rows / B rows >= N load from the 256B zero page.
// MFMA 16x16x32 bf16 (m89/m91): A/B lane holds [idx=lane&15][k=(lane>>4)*8+j];
// C/D: col=lane&15, row=(lane>>4)*4+reg.
// OUTMODE: 0 = bf16 C[row*ldc+col]; 1 = f32 TTS-transposed out[(b*80+col)*1024+f].
// ---------------------------------------------------------------------------
template<int BM, int BN, bool RELU, int OUTMODE>
__global__ __launch_bounds__(256)
void gemm_k(const u16* __restrict__ A, const u16* __restrict__ Bm,
            void* __restrict__ Cm, const float* __restrict__ bias,
            int M, int N, int K, int lda, int ldb, int ldc,
            float alpha, int Sseq, int ntaps, int dtap, long tapStrideB,
            const u16* __restrict__ zp,
            int zH, long sA1, long sA2, long sB1, long sB2, long sC1, long sC2)
{
  __shared__ u16 As[BM * 32];
  __shared__ u16 Bs[BN * 32];

  const int t = threadIdx.x;
  const int lane = t & 63;
  const int wave = t >> 6;
  constexpr int WCOLS = BN / 64;          // 2 (128-wide) or 1 (64-wide)
  const int wrow = wave / WCOLS;
  const int wcol = wave % WCOLS;
  const int bn0 = blockIdx.x * BN;
  const int bm0 = blockIdx.y * BM;
  const int z = blockIdx.z;
  const long offA = (long)(z / zH) * sA1 + (long)(z % zH) * sA2;
  const long offB = (long)(z / zH) * sB1 + (long)(z % zH) * sB2;
  const long offC = (long)(z / zH) * sC1 + (long)(z % zH) * sC2;

  floatx4 acc[4][4];
#pragma unroll
  for (int i = 0; i < 4; ++i)
#pragma unroll
    for (int j = 0; j < 4; ++j) acc[i][j] = (floatx4){0.f, 0.f, 0.f, 0.f};

  // staging lane decode: per 16-row wave pass, lane i covers row R0+(i>>2),
  // global granule (i&3)^((i>>3)&3)
  const int rsub = lane >> 2;
  const int g8 = (((lane & 3) ^ ((lane >> 3) & 3)) << 3);
  constexpr int PA = BM / 64, PB = BN / 64;

  // fragment-read swizzle (loop-invariant)
  const int q = lane >> 4, fm = lane & 15;
  const int swz8 = ((q ^ ((fm >> 1) & 3)) << 3);

  for (int tap = 0; tap < ntaps; ++tap) {
    const int dlt = tap - dtap;
    const u16* aP[PA]; const u16* bP[PB];
#pragma unroll
    for (int p = 0; p < PA; ++p) {
      int r = p * 64 + wave * 16 + rsub;
      int s = (bm0 + r) % Sseq;
      bool ok = (unsigned)(s + dlt) < (unsigned)Sseq;
      aP[p] = ok ? (A + offA + (long)(bm0 + r + dlt) * lda + g8) : nullptr;
    }
#pragma unroll
    for (int p = 0; p < PB; ++p) {
      int r = p * 64 + wave * 16 + rsub;
      bool ok = (bn0 + r) < N;
      bP[p] = ok ? (Bm + offB + (long)tap * tapStrideB + (long)(bn0 + r) * ldb + g8) : nullptr;
    }

    for (int k0 = 0; k0 < K; k0 += 32) {
#pragma unroll
      for (int p = 0; p < PA; ++p)
        gld16(aP[p] ? aP[p] + k0 : zp, &As[(p * 64 + wave * 16) * 32]);
#pragma unroll
      for (int p = 0; p < PB; ++p)
        gld16(bP[p] ? bP[p] + k0 : zp, &Bs[(p * 64 + wave * 16) * 32]);
      __syncthreads();

      short8 af[4], bfr[4];
#pragma unroll
      for (int i = 0; i < 4; ++i)
        af[i] = *(const short8*)&As[(wrow * 64 + i * 16 + fm) * 32 + swz8];
#pragma unroll
      for (int j = 0; j < 4; ++j)
        bfr[j] = *(const short8*)&Bs[(wcol * 64 + j * 16 + fm) * 32 + swz8];
#pragma unroll
      for (int i = 0; i < 4; ++i)
#pragma unroll
        for (int j = 0; j < 4; ++j)
          acc[i][j] = __builtin_amdgcn_mfma_f32_16x16x32_bf16(af[i], bfr[j], acc[i][j], 0, 0, 0);
      __syncthreads();
    }
  }

  const int rbase = bm0 + wrow * 64 + ((lane >> 4) << 2);
  const int cbase = bn0 + wcol * 64 + (lane & 15);
#pragma unroll
  for (int j = 0; j < 4; ++j) {
    int col = cbase + j * 16;
    if (col >= N) continue;
    float bv = bias ? bias[col] : 0.f;
#pragma unroll
    for (int i = 0; i < 4; ++i) {
#pragma unroll
      for (int r = 0; r < 4; ++r) {
        int row = rbase + i * 16 + r;
        float v = acc[i][j][r] * alpha + bv;
        if (RELU) v = fmaxf(v, 0.f);
        if (OUTMODE == 1) {
          // row = b*1024 + f ; out[b][col][f]
          ((float*)Cm)[((long)(row >> 10) * COUT + col) * CMEL + (row & 1023)] = v;
        } else {
          ((u16*)Cm)[offC + (long)row * ldc + col] = f2bf(v);
        }
      }
    }
  }
}

template<int BM, int BN, bool RELU, int OUTMODE>
static inline void launch_gemm(hipStream_t st, const u16* A, const u16* B, void* C,
                               const float* bias, int M, int N, int K,
                               int lda, int ldb, int ldc, float alpha,
                               int Sseq, int ntaps, int dtap, long tapB, const u16* zp,
                               int Z = 1, int zH = 1,
                               long sA1 = 0, long sA2 = 0, long sB1 = 0, long sB2 = 0,
                               long sC1 = 0, long sC2 = 0)
{
  dim3 grid((unsigned)((N + BN - 1) / BN), (unsigned)(M / BM), (unsigned)Z);
  gemm_k<BM, BN, RELU, OUTMODE><<<grid, dim3(256), 0, st>>>(
      A, B, C, bias, M, N, K, lda, ldb, ldc, alpha, Sseq, ntaps, dtap, tapB, zp,
      zH, sA1, sA2, sB1, sB2, sC1, sC2);
}

// ---------------------------------------------------------------------------
// W [tap][K][N] f32 -> WT [tap][N][K] bf16 (LDS-tiled 32x32 transpose)
__global__ void cvt_t_k(const float* __restrict__ src, u16* __restrict__ dst, int K, int N)
{
  const int tap = blockIdx.z;
  const int n0 = blockIdx.x * 32, k0 = blockIdx.y * 32;
  __shared__ float tile[32][33];
  const int t = threadIdx.x;
  const int c = t & 31, rr = t >> 5;   // rr 0..7
  const float* s = src + (long)tap * K * N;
  u16* d = dst + (long)tap * K * N;
#pragma unroll
  for (int i = 0; i < 4; ++i) {
    int k = k0 + rr + i * 8, n = n0 + c;
    tile[rr + i * 8][c] = (k < K && n < N) ? s[(long)k * N + n] : 0.f;
  }
  __syncthreads();
#pragma unroll
  for (int i = 0; i < 4; ++i) {
    int n = n0 + rr + i * 8, k = k0 + c;
    if (n < N && k < K) d[(long)n * K + k] = f2bf(tile[c][rr + i * 8]);
  }
}

// vt[(b*CH+h)*64 + d][S] = qkv[(b*S+s)*CQKV + 2*CD + h*64 + d]
__global__ void vtr_k(const u16* __restrict__ qkv, u16* __restrict__ vt, int S)
{
  const int s0 = blockIdx.x * 64;
  const int bh = blockIdx.y;           // b*CH + h
  const int b = bh >> 3, h = bh & 7;
  __shared__ u16 tile[64][65];
  const int t = threadIdx.x;
  const int wave = t >> 6, lane = t & 63;
#pragma unroll
  for (int i = 0; i < 16; ++i) {
    int sl = wave * 16 + i;
    tile[sl][lane] = qkv[(long)(b * S + s0 + sl) * CQKV + 2 * CD + h * 64 + lane];
  }
  __syncthreads();
  const int dl = t >> 2, sc4 = (t & 3) << 4;
  u16* dstp = vt + ((long)bh * 64 + dl) * S + s0 + sc4;
  short8 v0, v1;
#pragma unroll
  for (int j = 0; j < 8; ++j) { v0[j] = (short)tile[sc4 + j][dl]; v1[j] = (short)tile[sc4 + 8 + j][dl]; }
  *(short8*)dstp = v0;
  *(short8*)(dstp + 8) = v1;
}

__global__ void fill_k(float* __restrict__ o, int n, float v)
{
  int i = blockIdx.x * 256 + threadIdx.x;
  if (i < n) o[i] = v;
}

// x[b,t,:] = bf16( 2*emb[tok] + pos[b] )   (reference quirk: pos indexed by BATCH b)
__global__ void embed_k(const int* __restrict__ tok, const float* __restrict__ emb,
                        u16* __restrict__ X)
{
  const long idx = (long)blockIdx.x * 256 + threadIdx.x;  // < B*T*D
  const int d = (int)(idx & (CD - 1));
  const int m = (int)(idx >> 9);
  const int b = m >> 8;  // T = 256
  const float e = emb[(long)tok[m] * CD + d];
  const int i2 = d >> 1;
  const float den = __expf(-(float)(2 * i2) * (9.210340371976184f / 512.f));
  const float ang = (float)b * den;
  const float p = (d & 1) ? __cosf(ang) : __sinf(ang);
  X[idx] = f2bf(2.f * e + p);
}

// masked softmax over last dim, in place, bf16. grid (S, Z); b = z/zH
__global__ void softmax_k(u16* __restrict__ Sc, const int* __restrict__ lens, int S, int zH)
{
  const int qq = blockIdx.x, z = blockIdx.y, t = threadIdx.x;
  const int len = lens[z / zH];
  u16* row = Sc + ((long)z * S + qq) * S;
  const int nv = S >> 8;  // 1 (enc) or 4 (dec)
  float vals[4];
  float mx = -1e30f;
  for (int i = 0; i < nv; ++i) {
    int k = t + (i << 8);
    float v = (k <= len) ? bf2f(row[k]) : -1e30f;
    vals[i] = v; mx = fmaxf(mx, v);
  }
  __shared__ float red[256];
  red[t] = mx; __syncthreads();
  for (int s = 128; s > 0; s >>= 1) { if (t < s) red[t] = fmaxf(red[t], red[t + s]); __syncthreads(); }
  mx = red[0]; __syncthreads();
  float sum = 0.f;
  for (int i = 0; i < nv; ++i) { float e = __expf(vals[i] - mx); vals[i] = e; sum += e; }
  red[t] = sum; __syncthreads();
  for (int s = 128; s > 0; s >>= 1) { if (t < s) red[t] += red[t + s]; __syncthreads(); }
  const float inv = 1.f / red[0];
  for (int i = 0; i < nv; ++i) row[t + (i << 8)] = f2bf(vals[i] * inv);
}

// O = LN(X + Y) * g + b ; one block per row, D=512, f32 stats
__global__ void ln_res_k(const u16* __restrict__ X, const u16* __restrict__ Y,
                         const float* __restrict__ g, const float* __restrict__ bta,
                         u16* __restrict__ O)
{
  const int m = blockIdx.x, t = threadIdx.x;
  const long base = (long)m * CD;
  float v0 = bf2f(X[base + t]) + bf2f(Y[base + t]);
  float v1 = bf2f(X[base + t + 256]) + bf2f(Y[base + t + 256]);
  __shared__ float red[256];
  red[t] = v0 + v1; __syncthreads();
  for (int s = 128; s > 0; s >>= 1) { if (t < s) red[t] += red[t + s]; __syncthreads(); }
  const float mean = red[0] * (1.f / 512.f);
  __syncthreads();
  const float d0 = v0 - mean, d1 = v1 - mean;
  red[t] = d0 * d0 + d1 * d1; __syncthreads();
  for (int s = 128; s > 0; s >>= 1) { if (t < s) red[t] += red[t + s]; __syncthreads(); }
  const float rstd = rsqrtf(red[0] * (1.f / 512.f) + 1e-5f);
  O[base + t]       = f2bf(d0 * rstd * g[t] + bta[t]);
  O[base + t + 256] = f2bf(d1 * rstd * g[t + 256] + bta[t + 256]);
}

__global__ void cumsum_k(const int* __restrict__ dur, int* __restrict__ cums)
{
  int b = threadIdx.x;
  if (b < CB) {
    int s = 0;
    for (int t = 0; t < CT; ++t) { s += dur[b * CT + t]; cums[b * CT + t] = s; }
  }
}

// dec_in[b,f,:] = keep * enc[b, searchsorted_right(cums[b], f) (clipped), :]
__global__ void regulate_k(const u16* __restrict__ xe, const int* __restrict__ cums,
                           const int* __restrict__ mlen, u16* __restrict__ xd)
{
  const int m = blockIdx.x;      // b*MEL + f
  const int b = m >> 10, f = m & (CMEL - 1);
  int lo = 0, hi = CT;
  while (lo < hi) { int mid = (lo + hi) >> 1; if (cums[b * CT + mid] <= f) lo = mid + 1; else hi = mid; }
  const int idx = min(lo, CT - 1);
  const bool keep = (f <= mlen[b]);
  const u16* src = xe + ((long)b * CT + idx) * CD;
  u16* dst = xd + (long)m * CD;
  const int t = threadIdx.x;
  dst[t]       = keep ? src[t] : (u16)0;
  dst[t + 256] = keep ? src[t + 256] : (u16)0;
}

// ---------------------------------------------------------------------------
extern "C" void kernel_launch(void* const* d_in, const int* in_sizes, int n_in,
                              void* d_out, int out_size, void* d_ws, size_t ws_size,
                              hipStream_t stream)
{
  (void)in_sizes; (void)n_in;
  const int*   tokens = (const int*)d_in[0];
  const int*   tlen   = (const int*)d_in[1];
  const int*   mlen   = (const int*)d_in[2];
  const int*   dur    = (const int*)d_in[3];
  const float* emb    = (const float*)d_in[5];
  const float* ew[12]; const float* dw[12];
  for (int i = 0; i < 12; ++i) { ew[i] = (const float*)d_in[6 + i]; dw[i] = (const float*)d_in[18 + i]; }
  const float* out_w = (const float*)d_in[30];
  const float* out_b = (const float*)d_in[31];
  // stack weight idx: 0 wqkv,1 bqkv,2 wo,3 bo,4 ln1g,5 ln1b,6 c1w,7 c1b,8 c2w,9 c2b,10 ln2g,11 ln2b

  const int Me = CB * CT;       // 4096
  const int Md = CB * CMEL;     // 16384

  // ---- workspace layout (lifetime-aliased) ---------------------------------
  const size_t SZ_ZP   = 256;
  const size_t SZ_WBUF = (size_t)3 * CD * CINTER * 2;        // 6.3 MB (max weight)
  const size_t SZ_XE   = (size_t)Me * CD * 2;                // 4.2 MB
  const size_t SZ_XD   = (size_t)Md * CD * 2;                // 16.8 MB (x, x1, yb)
  const size_t SZ_QKV  = (size_t)Md * CQKV * 2;              // 50.3 MB
  const size_t SZ_HB   = (size_t)Md * CINTER * 2;            // 67.1 MB
  const size_t SZ_CUMS = (size_t)CB * CT * 4;
  auto al = [](size_t b) { return (b + 255) & ~(size_t)255; };

  auto totalFor = [&](int hch) -> size_t {
    size_t sc = (size_t)CB * hch * CMEL * CMEL * 2;
    size_t U = al(SZ_QKV) + al(sc);
    if (al(SZ_HB) > U) U = al(SZ_HB);
    return al(SZ_ZP) + al(SZ_WBUF) + al(SZ_XE) + 3 * al(SZ_XD) + U + al(SZ_CUMS);
  };
  int HCHv = 0;
  for (int h : {8, 4, 2, 1}) { if (totalFor(h) <= ws_size) { HCHv = h; break; } }
  if (HCHv == 0) {  // sentinel: absmax ~1000 => ws too small
    fill_k<<<dim3((unsigned)((out_size + 255) / 256)), dim3(256), 0, stream>>>(
        (float*)d_out, out_size, 1000.0f);
    return;
  }

  char* p = (char*)d_ws;
  auto take = [&](size_t bytes) { char* r = p; p += al(bytes); return r; };
  u16*  zp   = (u16*)take(SZ_ZP);
  u16*  wbuf = (u16*)take(SZ_WBUF);
  u16*  xe   = (u16*)take(SZ_XE);
  u16*  xd   = (u16*)take(SZ_XD);
  u16*  x1   = (u16*)take(SZ_XD);
  u16*  yb   = (u16*)take(SZ_XD);      // also aliases vt during attention
  char* U0   = take(0);
  u16*  qkvB = (u16*)U0;
  u16*  sc   = (u16*)(U0 + al(SZ_QKV));
  u16*  hb   = (u16*)U0;
  {
    size_t sc_sz = (size_t)CB * HCHv * CMEL * CMEL * 2;
    size_t U = al(SZ_QKV) + al(sc_sz);
    if (al(SZ_HB) > U) U = al(SZ_HB);
    (void)take(U);
  }
  int* cums = (int*)take(SZ_CUMS);

  hipMemsetAsync(zp, 0, SZ_ZP, stream);

  auto cvtT = [&](const float* s, u16* d, int K, int N, int taps) {
    cvt_t_k<<<dim3((unsigned)((N + 31) / 32), (unsigned)((K + 31) / 32), (unsigned)taps),
              dim3(256), 0, stream>>>(s, d, K, N);
  };

  embed_k<<<dim3((unsigned)((long)Me * CD / 256)), dim3(256), 0, stream>>>(tokens, emb, xe);

  auto run_stack = [&](u16* x, int S, int M, const int* lens, const float* const* W) {
    u16* vt = yb;   // yb dead during attention
    for (int l = 0; l < CL; ++l) {
      // qkv = x @ Wqkv + b
      cvtT(W[0] + (long)l * CD * CQKV, wbuf, CD, CQKV, 1);
      launch_gemm<128, 128, false, 0>(stream, x, wbuf, qkvB, W[1] + l * CQKV,
          M, CQKV, CD, CD, CD, CQKV, 1.f, M, 1, 0, 0, zp);
      // V^T for PV
      vtr_k<<<dim3((unsigned)(S / 64), (unsigned)(CB * CH)), dim3(256), 0, stream>>>(qkvB, vt, S);
      // attention, HCHv heads per chunk; PV overwrites consumed Q slice
      for (int c = 0; c < CH / HCHv; ++c) {
        const int h0 = c * HCHv;
        const int Z = CB * HCHv;
        launch_gemm<128, 128, false, 0>(stream,
            qkvB + h0 * CDH, qkvB + CD + h0 * CDH, sc, nullptr,
            S, S, CDH, CQKV, CQKV, S, 0.125f, S, 1, 0, 0, zp,
            Z, HCHv, (long)S * CQKV, CDH, (long)S * CQKV, CDH,
            (long)HCHv * S * S, (long)S * S);
        softmax_k<<<dim3((unsigned)S, (unsigned)Z), dim3(256), 0, stream>>>(sc, lens, S, HCHv);
        launch_gemm<256, 64, false, 0>(stream,
            sc, vt + (long)h0 * CDH * S, qkvB + h0 * CDH, nullptr,
            S, CDH, S, S, S, CQKV, 1.f, S, 1, 0, 0, zp,
            Z, HCHv, (long)HCHv * S * S, (long)S * S,
            (long)CH * CDH * S, (long)CDH * S,
            (long)S * CQKV, CDH);
      }
      // proj: ctx (= qkvB cols 0..511) @ Wo + bo
      cvtT(W[2] + (long)l * CD * CD, wbuf, CD, CD, 1);
      launch_gemm<128, 128, false, 0>(stream, qkvB, wbuf, yb, W[3] + l * CD,
          M, CD, CD, CQKV, CD, CD, 1.f, M, 1, 0, 0, zp);
      ln_res_k<<<dim3((unsigned)M), dim3(256), 0, stream>>>(x, yb, W[4] + l * CD, W[5] + l * CD, x1);
      // conv1 (3-tap) + relu
      cvtT(W[6] + (long)l * 3 * CD * CINTER, wbuf, CD, CINTER, 3);
      launch_gemm<128, 128, true, 0>(stream, x1, wbuf, hb, W[7] + l * CINTER,
          M, CINTER, CD, CD, CD, CINTER, 1.f, S, 3, 1, (long)CD * CINTER, zp);
      // conv2 (3-tap)
      cvtT(W[8] + (long)l * 3 * CINTER * CD, wbuf, CINTER, CD, 3);
      launch_gemm<128, 128, false, 0>(stream, hb, wbuf, yb, W[9] + l * CD,
          M, CD, CINTER, CINTER, CINTER, CD, 1.f, S, 3, 1, (long)CINTER * CD, zp);
      ln_res_k<<<dim3((unsigned)M), dim3(256), 0, stream>>>(x1, yb, W[10] + l * CD, W[11] + l * CD, x);
    }
  };

  run_stack(xe, CT, Me, tlen, ew);

  cumsum_k<<<dim3(1), dim3(64), 0, stream>>>(dur, cums);
  regulate_k<<<dim3((unsigned)(CB * CMEL)), dim3(256), 0, stream>>>(xe, cums, mlen, xd);

  run_stack(xd, CMEL, Md, mlen, dw);

  // final projection, transposed store straight to d_out (f32)
  cvtT(out_w, wbuf, CD, COUT, 1);
  launch_gemm<128, 128, false, 1>(stream, xd, wbuf, d_out, out_b,
      Md, COUT, CD, CD, CD, COUT, 1.f, Md, 1, 0, 0, zp);
}

// Round 4
// 4480.115 us; speedup vs baseline: 2.5723x; 1.0502x over previous
//
#include <hip/hip_runtime.h>

typedef unsigned short u16;
typedef short short8 __attribute__((ext_vector_type(8)));
typedef float floatx4 __attribute__((ext_vector_type(4)));

static constexpr int CB = 16, CT = 256, CMEL = 1024, CD = 512, CH = 8, CDH = 64, CL = 4;
static constexpr int CINTER = 2048, COUT = 80;
static constexpr int CQKV = 3 * CH * CDH;   // 1536

static __device__ __forceinline__ float bf2f(u16 u) {
  union { unsigned u; float f; } v; v.u = ((unsigned)u) << 16; return v.f;
}
static __device__ __forceinline__ u16 f2bf(float f) {  // RNE; inputs finite
  union { float f; unsigned u; } v; v.f = f;
  unsigned r = v.u + 0x7fffu + ((v.u >> 16) & 1u);
  return (u16)(r >> 16);
}

// async global->LDS, 16B per lane; LDS dest = wave-uniform base + lane*16 (m104/m108)
static __device__ __forceinline__ void gld16(const u16* g, u16* lds) {
  __builtin_amdgcn_global_load_lds((const __attribute__((address_space(1))) void*)g,
                                   (__attribute__((address_space(3))) void*)lds, 16, 0, 0);
}

// ===========================================================================
// gemm2_k: 256x128-tile, 8-wave (512 thr) bf16 MFMA GEMM with folded conv taps.
// A: M x K row-major. B: [tap][N][K] (weights pre-transposed). C: M x N bf16.
// NT=1: plain GEMM (no halo, no masking). NT=3: SAME conv1d, dtap=1.
// A staged once per k0 with +-8-row halo (272 rows, 17 chunks; wave0 takes #16).
// LDS granule swizzle: row r, global granule g at slot g ^ (((r&15)>>1)&3).
// Tap validity (s+dlt in [0,S)) via fragment zeroing; S power of 2 (Sm1 mask).
// MFMA 16x16x32 bf16 (m89/m91): A/B lane [idx=lane&15][k=(lane>>4)*8+j];
// C/D col=lane&15, row=(lane>>4)*4+reg.
// ===========================================================================
template<int NT, bool RELU>
__global__ __launch_bounds__(512)
void gemm2_k(const u16* __restrict__ A, const u16* __restrict__ Bm,
             u16* __restrict__ Cm, const float* __restrict__ bias,
             int M, int N, int K, int lda, int ldb, int ldc,
             int Sm1, long tapStrideB, const u16* __restrict__ zp)
{
  constexpr int BM = 256, BN = 128;
  constexpr int H = (NT == 3) ? 8 : 0;
  constexpr int AR = BM + 2 * H;           // 272 or 256
  __shared__ u16 As[AR * 32];
  __shared__ u16 Bs[NT * BN * 32];

  const int t = threadIdx.x;
  const int lane = t & 63;
  const int wave = t >> 6;                 // 0..7
  const int wrow = wave >> 1;              // 0..3 (64-row group)
  const int wcol = wave & 1;               // 0..1 (64-col group)
  const int bn0 = blockIdx.x * BN;
  const int bm0 = blockIdx.y * BM;

  floatx4 acc[4][4];
#pragma unroll
  for (int i = 0; i < 4; ++i)
#pragma unroll
    for (int j = 0; j < 4; ++j) acc[i][j] = (floatx4){0.f, 0.f, 0.f, 0.f};

  const int rsub = lane >> 2;
  const int g8 = (((lane & 3) ^ ((lane >> 3) & 3)) << 3);

  // ---- A chunk pointers (tap-independent; halo covers all taps)
  const u16* aP0; const u16* aP1; const u16* aP2 = nullptr;
  {
    int gg0 = bm0 - H + wave * 16 + rsub;
    int gg1 = bm0 - H + (wave + 8) * 16 + rsub;
    aP0 = ((NT == 1) || ((unsigned)gg0 < (unsigned)M)) ? A + (long)gg0 * lda + g8 : nullptr;
    aP1 = ((NT == 1) || ((unsigned)gg1 < (unsigned)M)) ? A + (long)gg1 * lda + g8 : nullptr;
    if (NT == 3 && wave == 0) {
      int gg2 = bm0 - H + 256 + rsub;      // chunk 16
      aP2 = ((unsigned)gg2 < (unsigned)M) ? A + (long)gg2 * lda + g8 : nullptr;
    }
  }
  const int aL0 = wave * 512, aL1 = (wave + 8) * 512, aL2 = 16 * 512;

  // ---- B chunk pointers: chunk c = tap*8 + wave -> rows [tap][wave*16..+16)
  const u16* bP[NT]; int bL[NT];
#pragma unroll
  for (int i = 0; i < NT; ++i) {
    bP[i] = Bm + (long)i * tapStrideB + (long)(bn0 + wave * 16 + rsub) * ldb + g8;
    bL[i] = (i * BN + wave * 16) * 32;
  }

  // ---- fragment decode, swizzle keys, tap masks
  const int q = lane >> 4, fm = lane & 15;
  const int swzB = (q ^ ((fm >> 1) & 3)) << 3;
  int swzA[NT];
  bool mv[NT][4];
#pragma unroll
  for (int tap = 0; tap < NT; ++tap) {
    const int dlt = tap - ((NT == 3) ? 1 : 0);
    swzA[tap] = (q ^ ((((H + dlt + fm) & 15) >> 1) & 3)) << 3;
#pragma unroll
    for (int i = 0; i < 4; ++i) {
      int s = (bm0 + wrow * 64 + i * 16 + fm) & Sm1;
      mv[tap][i] = ((unsigned)(s + dlt) <= (unsigned)Sm1);
    }
  }
  const short8 zero8 = {};

  for (int k0 = 0; k0 < K; k0 += 32) {
    gld16(aP0 ? aP0 + k0 : zp, &As[aL0]);
    gld16(aP1 ? aP1 + k0 : zp, &As[aL1]);
    if (NT == 3 && wave == 0) gld16(aP2 ? aP2 + k0 : zp, &As[aL2]);
#pragma unroll
    for (int i = 0; i < NT; ++i) gld16(bP[i] + k0, &Bs[bL[i]]);
    __syncthreads();

#pragma unroll
    for (int tap = 0; tap < NT; ++tap) {
      const int dlt = tap - ((NT == 3) ? 1 : 0);
      short8 af[4], bfr[4];
#pragma unroll
      for (int i = 0; i < 4; ++i) {
        af[i] = *(const short8*)&As[(wrow * 64 + i * 16 + fm + H + dlt) * 32 + swzA[tap]];
        if (NT == 3 && !mv[tap][i]) af[i] = zero8;
      }
#pragma unroll
      for (int j = 0; j < 4; ++j)
        bfr[j] = *(const short8*)&Bs[(tap * BN + wcol * 64 + j * 16 + fm) * 32 + swzB];
#pragma unroll
      for (int i = 0; i < 4; ++i)
#pragma unroll
        for (int j = 0; j < 4; ++j)
          acc[i][j] = __builtin_amdgcn_mfma_f32_16x16x32_bf16(af[i], bfr[j], acc[i][j], 0, 0, 0);
    }
    __syncthreads();
  }

  const int rbase = bm0 + wrow * 64 + ((lane >> 4) << 2);
  const int cbase = bn0 + wcol * 64 + fm;
#pragma unroll
  for (int j = 0; j < 4; ++j) {
    int col = cbase + j * 16;              // N multiple of 128 for all gemm2 uses
    float bv = bias ? bias[col] : 0.f;
#pragma unroll
    for (int i = 0; i < 4; ++i) {
#pragma unroll
      for (int r = 0; r < 4; ++r) {
        int row = rbase + i * 16 + r;
        float v = acc[i][j][r] + bv;
        if (RELU) v = fmaxf(v, 0.f);
        Cm[(long)row * ldc + col] = f2bf(v);
      }
    }
  }
}

// ---------------------------------------------------------------------------
// Legacy 128-tile GEMM (attention QK/PV, final out-proj). Both operands N x K
// row-major. Batched via blockIdx.z. OUTMODE 1 = f32 transposed final store.
// ---------------------------------------------------------------------------
template<int BM, int BN, bool RELU, int OUTMODE>
__global__ __launch_bounds__(256)
void gemm_k(const u16* __restrict__ A, const u16* __restrict__ Bm,
            void* __restrict__ Cm, const float* __restrict__ bias,
            int M, int N, int K, int lda, int ldb, int ldc,
            float alpha, int Sseq, int ntaps, int dtap, long tapStrideB,
            const u16* __restrict__ zp,
            int zH, long sA1, long sA2, long sB1, long sB2, long sC1, long sC2)
{
  __shared__ u16 As[BM * 32];
  __shared__ u16 Bs[BN * 32];

  const int t = threadIdx.x;
  const int lane = t & 63;
  const int wave = t >> 6;
  constexpr int WCOLS = BN / 64;
  const int wrow = wave / WCOLS;
  const int wcol = wave % WCOLS;
  const int bn0 = blockIdx.x * BN;
  const int bm0 = blockIdx.y * BM;
  const int z = blockIdx.z;
  const long offA = (long)(z / zH) * sA1 + (long)(z % zH) * sA2;
  const long offB = (long)(z / zH) * sB1 + (long)(z % zH) * sB2;
  const long offC = (long)(z / zH) * sC1 + (long)(z % zH) * sC2;

  floatx4 acc[4][4];
#pragma unroll
  for (int i = 0; i < 4; ++i)
#pragma unroll
    for (int j = 0; j < 4; ++j) acc[i][j] = (floatx4){0.f, 0.f, 0.f, 0.f};

  const int rsub = lane >> 2;
  const int g8 = (((lane & 3) ^ ((lane >> 3) & 3)) << 3);
  constexpr int PA = BM / 64, PB = BN / 64;

  const int q = lane >> 4, fm = lane & 15;
  const int swz8 = ((q ^ ((fm >> 1) & 3)) << 3);

  for (int tap = 0; tap < ntaps; ++tap) {
    const int dlt = tap - dtap;
    const u16* aP[PA]; const u16* bP[PB];
#pragma unroll
    for (int p = 0; p < PA; ++p) {
      int r = p * 64 + wave * 16 + rsub;
      int s = (bm0 + r) % Sseq;
      bool ok = (unsigned)(s + dlt) < (unsigned)Sseq;
      aP[p] = ok ? (A + offA + (long)(bm0 + r + dlt) * lda + g8) : nullptr;
    }
#pragma unroll
    for (int p = 0; p < PB; ++p) {
      int r = p * 64 + wave * 16 + rsub;
      bool ok = (bn0 + r) < N;
      bP[p] = ok ? (Bm + offB + (long)tap * tapStrideB + (long)(bn0 + r) * ldb + g8) : nullptr;
    }

    for (int k0 = 0; k0 < K; k0 += 32) {
#pragma unroll
      for (int p = 0; p < PA; ++p)
        gld16(aP[p] ? aP[p] + k0 : zp, &As[(p * 64 + wave * 16) * 32]);
#pragma unroll
      for (int p = 0; p < PB; ++p)
        gld16(bP[p] ? bP[p] + k0 : zp, &Bs[(p * 64 + wave * 16) * 32]);
      __syncthreads();

      short8 af[4], bfr[4];
#pragma unroll
      for (int i = 0; i < 4; ++i)
        af[i] = *(const short8*)&As[(wrow * 64 + i * 16 + fm) * 32 + swz8];
#pragma unroll
      for (int j = 0; j < 4; ++j)
        bfr[j] = *(const short8*)&Bs[(wcol * 64 + j * 16 + fm) * 32 + swz8];
#pragma unroll
      for (int i = 0; i < 4; ++i)
#pragma unroll
        for (int j = 0; j < 4; ++j)
          acc[i][j] = __builtin_amdgcn_mfma_f32_16x16x32_bf16(af[i], bfr[j], acc[i][j], 0, 0, 0);
      __syncthreads();
    }
  }

  const int rbase = bm0 + wrow * 64 + ((lane >> 4) << 2);
  const int cbase = bn0 + wcol * 64 + (lane & 15);
#pragma unroll
  for (int j = 0; j < 4; ++j) {
    int col = cbase + j * 16;
    if (col >= N) continue;
    float bv = bias ? bias[col] : 0.f;
#pragma unroll
    for (int i = 0; i < 4; ++i) {
#pragma unroll
      for (int r = 0; r < 4; ++r) {
        int row = rbase + i * 16 + r;
        float v = acc[i][j][r] * alpha + bv;
        if (RELU) v = fmaxf(v, 0.f);
        if (OUTMODE == 1) {
          ((float*)Cm)[((long)(row >> 10) * COUT + col) * CMEL + (row & 1023)] = v;
        } else {
          ((u16*)Cm)[offC + (long)row * ldc + col] = f2bf(v);
        }
      }
    }
  }
}

template<int BM, int BN, bool RELU, int OUTMODE>
static inline void launch_gemm(hipStream_t st, const u16* A, const u16* B, void* C,
                               const float* bias, int M, int N, int K,
                               int lda, int ldb, int ldc, float alpha,
                               int Sseq, int ntaps, int dtap, long tapB, const u16* zp,
                               int Z = 1, int zH = 1,
                               long sA1 = 0, long sA2 = 0, long sB1 = 0, long sB2 = 0,
                               long sC1 = 0, long sC2 = 0)
{
  dim3 grid((unsigned)((N + BN - 1) / BN), (unsigned)(M / BM), (unsigned)Z);
  gemm_k<BM, BN, RELU, OUTMODE><<<grid, dim3(256), 0, st>>>(
      A, B, C, bias, M, N, K, lda, ldb, ldc, alpha, Sseq, ntaps, dtap, tapB, zp,
      zH, sA1, sA2, sB1, sB2, sC1, sC2);
}

// ---------------------------------------------------------------------------
// W [tap][K][N] f32 -> WT [tap][N][K] bf16 (LDS-tiled 32x32 transpose)
__global__ void cvt_t_k(const float* __restrict__ src, u16* __restrict__ dst, int K, int N)
{
  const int tap = blockIdx.z;
  const int n0 = blockIdx.x * 32, k0 = blockIdx.y * 32;
  __shared__ float tile[32][33];
  const int t = threadIdx.x;
  const int c = t & 31, rr = t >> 5;   // rr 0..7
  const float* s = src + (long)tap * K * N;
  u16* d = dst + (long)tap * K * N;
#pragma unroll
  for (int i = 0; i < 4; ++i) {
    int k = k0 + rr + i * 8, n = n0 + c;
    tile[rr + i * 8][c] = (k < K && n < N) ? s[(long)k * N + n] : 0.f;
  }
  __syncthreads();
#pragma unroll
  for (int i = 0; i < 4; ++i) {
    int n = n0 + rr + i * 8, k = k0 + c;
    if (n < N && k < K) d[(long)n * K + k] = f2bf(tile[c][rr + i * 8]);
  }
}

// vt[(b*CH+h)*64 + d][S] = qkv[(b*S+s)*CQKV + 2*CD + h*64 + d]
__global__ void vtr_k(const u16* __restrict__ qkv, u16* __restrict__ vt, int S)
{
  const int s0 = blockIdx.x * 64;
  const int bh = blockIdx.y;           // b*CH + h
  const int b = bh >> 3, h = bh & 7;
  __shared__ u16 tile[64][65];
  const int t = threadIdx.x;
  const int wave = t >> 6, lane = t & 63;
#pragma unroll
  for (int i = 0; i < 16; ++i) {
    int sl = wave * 16 + i;
    tile[sl][lane] = qkv[(long)(b * S + s0 + sl) * CQKV + 2 * CD + h * 64 + lane];
  }
  __syncthreads();
  const int dl = t >> 2, sc4 = (t & 3) << 4;
  u16* dstp = vt + ((long)bh * 64 + dl) * S + s0 + sc4;
  short8 v0, v1;
#pragma unroll
  for (int j = 0; j < 8; ++j) { v0[j] = (short)tile[sc4 + j][dl]; v1[j] = (short)tile[sc4 + 8 + j][dl]; }
  *(short8*)dstp = v0;
  *(short8*)(dstp + 8) = v1;
}

__global__ void fill_k(float* __restrict__ o, int n, float v)
{
  int i = blockIdx.x * 256 + threadIdx.x;
  if (i < n) o[i] = v;
}

// x[b,t,:] = bf16( 2*emb[tok] + pos[b] )   (reference quirk: pos indexed by BATCH b)
__global__ void embed_k(const int* __restrict__ tok, const float* __restrict__ emb,
                        u16* __restrict__ X)
{
  const long idx = (long)blockIdx.x * 256 + threadIdx.x;  // < B*T*D
  const int d = (int)(idx & (CD - 1));
  const int m = (int)(idx >> 9);
  const int b = m >> 8;  // T = 256
  const float e = emb[(long)tok[m] * CD + d];
  const int i2 = d >> 1;
  const float den = __expf(-(float)(2 * i2) * (9.210340371976184f / 512.f));
  const float ang = (float)b * den;
  const float p = (d & 1) ? __cosf(ang) : __sinf(ang);
  X[idx] = f2bf(2.f * e + p);
}

// masked softmax over last dim, in place, bf16. grid (S, Z); b = z/zH
__global__ void softmax_k(u16* __restrict__ Sc, const int* __restrict__ lens, int S, int zH)
{
  const int qq = blockIdx.x, z = blockIdx.y, t = threadIdx.x;
  const int len = lens[z / zH];
  u16* row = Sc + ((long)z * S + qq) * S;
  const int nv = S >> 8;  // 1 (enc) or 4 (dec)
  float vals[4];
  float mx = -1e30f;
  for (int i = 0; i < nv; ++i) {
    int k = t + (i << 8);
    float v = (k <= len) ? bf2f(row[k]) : -1e30f;
    vals[i] = v; mx = fmaxf(mx, v);
  }
  __shared__ float red[256];
  red[t] = mx; __syncthreads();
  for (int s = 128; s > 0; s >>= 1) { if (t < s) red[t] = fmaxf(red[t], red[t + s]); __syncthreads(); }
  mx = red[0]; __syncthreads();
  float sum = 0.f;
  for (int i = 0; i < nv; ++i) { float e = __expf(vals[i] - mx); vals[i] = e; sum += e; }
  red[t] = sum; __syncthreads();
  for (int s = 128; s > 0; s >>= 1) { if (t < s) red[t] += red[t + s]; __syncthreads(); }
  const float inv = 1.f / red[0];
  for (int i = 0; i < nv; ++i) row[t + (i << 8)] = f2bf(vals[i] * inv);
}

// O = LN(X + Y) * g + b ; one block per row, D=512, f32 stats
__global__ void ln_res_k(const u16* __restrict__ X, const u16* __restrict__ Y,
                         const float* __restrict__ g, const float* __restrict__ bta,
                         u16* __restrict__ O)
{
  const int m = blockIdx.x, t = threadIdx.x;
  const long base = (long)m * CD;
  float v0 = bf2f(X[base + t]) + bf2f(Y[base + t]);
  float v1 = bf2f(X[base + t + 256]) + bf2f(Y[base + t + 256]);
  __shared__ float red[256];
  red[t] = v0 + v1; __syncthreads();
  for (int s = 128; s > 0; s >>= 1) { if (t < s) red[t] += red[t + s]; __syncthreads(); }
  const float mean = red[0] * (1.f / 512.f);
  __syncthreads();
  const float d0 = v0 - mean, d1 = v1 - mean;
  red[t] = d0 * d0 + d1 * d1; __syncthreads();
  for (int s = 128; s > 0; s >>= 1) { if (t < s) red[t] += red[t + s]; __syncthreads(); }
  const float rstd = rsqrtf(red[0] * (1.f / 512.f) + 1e-5f);
  O[base + t]       = f2bf(d0 * rstd * g[t] + bta[t]);
  O[base + t + 256] = f2bf(d1 * rstd * g[t + 256] + bta[t + 256]);
}

__global__ void cumsum_k(const int* __restrict__ dur, int* __restrict__ cums)
{
  int b = threadIdx.x;
  if (b < CB) {
    int s = 0;
    for (int t = 0; t < CT; ++t) { s += dur[b * CT + t]; cums[b * CT + t] = s; }
  }
}

// dec_in[b,f,:] = keep * enc[b, searchsorted_right(cums[b], f) (clipped), :]
__global__ void regulate_k(const u16* __restrict__ xe, const int* __restrict__ cums,
                           const int* __restrict__ mlen, u16* __restrict__ xd)
{
  const int m = blockIdx.x;      // b*MEL + f
  const int b = m >> 10, f = m & (CMEL - 1);
  int lo = 0, hi = CT;
  while (lo < hi) { int mid = (lo + hi) >> 1; if (cums[b * CT + mid] <= f) lo = mid + 1; else hi = mid; }
  const int idx = min(lo, CT - 1);
  const bool keep = (f <= mlen[b]);
  const u16* src = xe + ((long)b * CT + idx) * CD;
  u16* dst = xd + (long)m * CD;
  const int t = threadIdx.x;
  dst[t]       = keep ? src[t] : (u16)0;
  dst[t + 256] = keep ? src[t + 256] : (u16)0;
}

// ---------------------------------------------------------------------------
extern "C" void kernel_launch(void* const* d_in, const int* in_sizes, int n_in,
                              void* d_out, int out_size, void* d_ws, size_t ws_size,
                              hipStream_t stream)
{
  (void)in_sizes; (void)n_in;
  const int*   tokens = (const int*)d_in[0];
  const int*   tlen   = (const int*)d_in[1];
  const int*   mlen   = (const int*)d_in[2];
  const int*   dur    = (const int*)d_in[3];
  const float* emb    = (const float*)d_in[5];
  const float* ew[12]; const float* dw[12];
  for (int i = 0; i < 12; ++i) { ew[i] = (const float*)d_in[6 + i]; dw[i] = (const float*)d_in[18 + i]; }
  const float* out_w = (const float*)d_in[30];
  const float* out_b = (const float*)d_in[31];
  // stack weight idx: 0 wqkv,1 bqkv,2 wo,3 bo,4 ln1g,5 ln1b,6 c1w,7 c1b,8 c2w,9 c2b,10 ln2g,11 ln2b

  const int Me = CB * CT;       // 4096
  const int Md = CB * CMEL;     // 16384

  // ---- workspace layout (lifetime-aliased) ---------------------------------
  const size_t SZ_ZP   = 256;
  const size_t SZ_WBUF = (size_t)3 * CD * CINTER * 2;        // 6.3 MB (max weight)
  const size_t SZ_XE   = (size_t)Me * CD * 2;                // 4.2 MB
  const size_t SZ_XD   = (size_t)Md * CD * 2;                // 16.8 MB (x, x1, yb)
  const size_t SZ_QKV  = (size_t)Md * CQKV * 2;              // 50.3 MB
  const size_t SZ_HB   = (size_t)Md * CINTER * 2;            // 67.1 MB
  const size_t SZ_CUMS = (size_t)CB * CT * 4;
  auto al = [](size_t b) { return (b + 255) & ~(size_t)255; };

  auto totalFor = [&](int hch) -> size_t {
    size_t sc = (size_t)CB * hch * CMEL * CMEL * 2;
    size_t U = al(SZ_QKV) + al(sc);
    if (al(SZ_HB) > U) U = al(SZ_HB);
    return al(SZ_ZP) + al(SZ_WBUF) + al(SZ_XE) + 3 * al(SZ_XD) + U + al(SZ_CUMS);
  };
  int HCHv = 0;
  for (int h : {8, 4, 2, 1}) { if (totalFor(h) <= ws_size) { HCHv = h; break; } }
  if (HCHv == 0) {  // sentinel: absmax ~1000 => ws too small
    fill_k<<<dim3((unsigned)((out_size + 255) / 256)), dim3(256), 0, stream>>>(
        (float*)d_out, out_size, 1000.0f);
    return;
  }

  char* p = (char*)d_ws;
  auto take = [&](size_t bytes) { char* r = p; p += al(bytes); return r; };
  u16*  zp   = (u16*)take(SZ_ZP);
  u16*  wbuf = (u16*)take(SZ_WBUF);
  u16*  xe   = (u16*)take(SZ_XE);
  u16*  xd   = (u16*)take(SZ_XD);
  u16*  x1   = (u16*)take(SZ_XD);
  u16*  yb   = (u16*)take(SZ_XD);      // also aliases vt during attention
  char* U0   = take(0);
  u16*  qkvB = (u16*)U0;
  u16*  sc   = (u16*)(U0 + al(SZ_QKV));
  u16*  hb   = (u16*)U0;
  {
    size_t sc_sz = (size_t)CB * HCHv * CMEL * CMEL * 2;
    size_t U = al(SZ_QKV) + al(sc_sz);
    if (al(SZ_HB) > U) U = al(SZ_HB);
    (void)take(U);
  }
  int* cums = (int*)take(SZ_CUMS);

  hipMemsetAsync(zp, 0, SZ_ZP, stream);

  auto cvtT = [&](const float* s, u16* d, int K, int N, int taps) {
    cvt_t_k<<<dim3((unsigned)((N + 31) / 32), (unsigned)((K + 31) / 32), (unsigned)taps),
              dim3(256), 0, stream>>>(s, d, K, N);
  };

  embed_k<<<dim3((unsigned)((long)Me * CD / 256)), dim3(256), 0, stream>>>(tokens, emb, xe);

  auto run_stack = [&](u16* x, int S, int M, const int* lens, const float* const* W) {
    u16* vt = yb;   // yb dead during attention
    for (int l = 0; l < CL; ++l) {
      // qkv = x @ Wqkv + b
      cvtT(W[0] + (long)l * CD * CQKV, wbuf, CD, CQKV, 1);
      gemm2_k<1, false><<<dim3(CQKV / 128, M / 256), dim3(512), 0, stream>>>(
          x, wbuf, qkvB, W[1] + l * CQKV, M, CQKV, CD, CD, CD, CQKV, S - 1, 0, zp);
      // V^T for PV
      vtr_k<<<dim3((unsigned)(S / 64), (unsigned)(CB * CH)), dim3(256), 0, stream>>>(qkvB, vt, S);
      // attention, HCHv heads per chunk; PV overwrites consumed Q slice
      for (int c = 0; c < CH / HCHv; ++c) {
        const int h0 = c * HCHv;
        const int Z = CB * HCHv;
        launch_gemm<128, 128, false, 0>(stream,
            qkvB + h0 * CDH, qkvB + CD + h0 * CDH, sc, nullptr,
            S, S, CDH, CQKV, CQKV, S, 0.125f, S, 1, 0, 0, zp,
            Z, HCHv, (long)S * CQKV, CDH, (long)S * CQKV, CDH,
            (long)HCHv * S * S, (long)S * S);
        softmax_k<<<dim3((unsigned)S, (unsigned)Z), dim3(256), 0, stream>>>(sc, lens, S, HCHv);
        launch_gemm<256, 64, false, 0>(stream,
            sc, vt + (long)h0 * CDH * S, qkvB + h0 * CDH, nullptr,
            S, CDH, S, S, S, CQKV, 1.f, S, 1, 0, 0, zp,
            Z, HCHv, (long)HCHv * S * S, (long)S * S,
            (long)CH * CDH * S, (long)CDH * S,
            (long)S * CQKV, CDH);
      }
      // proj: ctx (= qkvB cols 0..511) @ Wo + bo
      cvtT(W[2] + (long)l * CD * CD, wbuf, CD, CD, 1);
      gemm2_k<1, false><<<dim3(CD / 128, M / 256), dim3(512), 0, stream>>>(
          qkvB, wbuf, yb, W[3] + l * CD, M, CD, CD, CQKV, CD, CD, S - 1, 0, zp);
      ln_res_k<<<dim3((unsigned)M), dim3(256), 0, stream>>>(x, yb, W[4] + l * CD, W[5] + l * CD, x1);
      // conv1 (3-tap) + relu
      cvtT(W[6] + (long)l * 3 * CD * CINTER, wbuf, CD, CINTER, 3);
      gemm2_k<3, true><<<dim3(CINTER / 128, M / 256), dim3(512), 0, stream>>>(
          x1, wbuf, hb, W[7] + l * CINTER, M, CINTER, CD, CD, CD, CINTER,
          S - 1, (long)CD * CINTER, zp);
      // conv2 (3-tap)
      cvtT(W[8] + (long)l * 3 * CINTER * CD, wbuf, CINTER, CD, 3);
      gemm2_k<3, false><<<dim3(CD / 128, M / 256), dim3(512), 0, stream>>>(
          hb, wbuf, yb, W[9] + l * CD, M, CD, CINTER, CINTER, CINTER, CD,
          S - 1, (long)CINTER * CD, zp);
      ln_res_k<<<dim3((unsigned)M), dim3(256), 0, stream>>>(x1, yb, W[10] + l * CD, W[11] + l * CD, x);
    }
  };

  run_stack(xe, CT, Me, tlen, ew);

  cumsum_k<<<dim3(1), dim3(64), 0, stream>>>(dur, cums);
  regulate_k<<<dim3((unsigned)(CB * CMEL)), dim3(256), 0, stream>>>(xe, cums, mlen, xd);

  run_stack(xd, CMEL, Md, mlen, dw);

  // final projection, transposed store straight to d_out (f32)
  cvtT(out_w, wbuf, CD, COUT, 1);
  launch_gemm<128, 128, false, 1>(stream, xd, wbuf, d_out, out_b,
      Md, COUT, CD, CD, CD, COUT, 1.f, Md, 1, 0, 0, zp);
}

// Round 5
// 2890.899 us; speedup vs baseline: 3.9864x; 1.5497x over previous
//
#include <hip/hip_runtime.h>

typedef unsigned short u16;
typedef short short8 __attribute__((ext_vector_type(8)));
typedef float floatx4 __attribute__((ext_vector_type(4)));

static constexpr int CB = 16, CT = 256, CMEL = 1024, CD = 512, CH = 8, CDH = 64, CL = 4;
static constexpr int CINTER = 2048, COUT = 80;
static constexpr int CQKV = 3 * CH * CDH;   // 1536

static __device__ __forceinline__ float bf2f(u16 u) {
  union { unsigned u; float f; } v; v.u = ((unsigned)u) << 16; return v.f;
}
static __device__ __forceinline__ u16 f2bf(float f) {  // RNE; inputs finite
  union { float f; unsigned u; } v; v.f = f;
  unsigned r = v.u + 0x7fffu + ((v.u >> 16) & 1u);
  return (u16)(r >> 16);
}

// async global->LDS, 16B per lane; LDS dest = wave-uniform base + lane*16 (m104/m108)
static __device__ __forceinline__ void gld16(const u16* g, u16* lds) {
  __builtin_amdgcn_global_load_lds((const __attribute__((address_space(1))) void*)g,
                                   (__attribute__((address_space(3))) void*)lds, 16, 0, 0);
}

// ===========================================================================
// gemm2_k: 256x128-tile, 8-wave bf16 MFMA GEMM with folded conv taps (R4).
// ===========================================================================
template<int NT, bool RELU>
__global__ __launch_bounds__(512)
void gemm2_k(const u16* __restrict__ A, const u16* __restrict__ Bm,
             u16* __restrict__ Cm, const float* __restrict__ bias,
             int M, int N, int K, int lda, int ldb, int ldc,
             int Sm1, long tapStrideB, const u16* __restrict__ zp)
{
  constexpr int BM = 256, BN = 128;
  constexpr int H = (NT == 3) ? 8 : 0;
  constexpr int AR = BM + 2 * H;
  __shared__ u16 As[AR * 32];
  __shared__ u16 Bs[NT * BN * 32];

  const int t = threadIdx.x;
  const int lane = t & 63;
  const int wave = t >> 6;
  const int wrow = wave >> 1;
  const int wcol = wave & 1;
  const int bn0 = blockIdx.x * BN;
  const int bm0 = blockIdx.y * BM;

  floatx4 acc[4][4];
#pragma unroll
  for (int i = 0; i < 4; ++i)
#pragma unroll
    for (int j = 0; j < 4; ++j) acc[i][j] = (floatx4){0.f, 0.f, 0.f, 0.f};

  const int rsub = lane >> 2;
  const int g8 = (((lane & 3) ^ ((lane >> 3) & 3)) << 3);

  const u16* aP0; const u16* aP1; const u16* aP2 = nullptr;
  {
    int gg0 = bm0 - H + wave * 16 + rsub;
    int gg1 = bm0 - H + (wave + 8) * 16 + rsub;
    aP0 = ((NT == 1) || ((unsigned)gg0 < (unsigned)M)) ? A + (long)gg0 * lda + g8 : nullptr;
    aP1 = ((NT == 1) || ((unsigned)gg1 < (unsigned)M)) ? A + (long)gg1 * lda + g8 : nullptr;
    if (NT == 3 && wave == 0) {
      int gg2 = bm0 - H + 256 + rsub;
      aP2 = ((unsigned)gg2 < (unsigned)M) ? A + (long)gg2 * lda + g8 : nullptr;
    }
  }
  const int aL0 = wave * 512, aL1 = (wave + 8) * 512, aL2 = 16 * 512;

  const u16* bP[NT]; int bL[NT];
#pragma unroll
  for (int i = 0; i < NT; ++i) {
    bP[i] = Bm + (long)i * tapStrideB + (long)(bn0 + wave * 16 + rsub) * ldb + g8;
    bL[i] = (i * BN + wave * 16) * 32;
  }

  const int q = lane >> 4, fm = lane & 15;
  const int swzB = (q ^ ((fm >> 1) & 3)) << 3;
  int swzA[NT];
  bool mv[NT][4];
#pragma unroll
  for (int tap = 0; tap < NT; ++tap) {
    const int dlt = tap - ((NT == 3) ? 1 : 0);
    swzA[tap] = (q ^ ((((H + dlt + fm) & 15) >> 1) & 3)) << 3;
#pragma unroll
    for (int i = 0; i < 4; ++i) {
      int s = (bm0 + wrow * 64 + i * 16 + fm) & Sm1;
      mv[tap][i] = ((unsigned)(s + dlt) <= (unsigned)Sm1);
    }
  }
  const short8 zero8 = {};

  for (int k0 = 0; k0 < K; k0 += 32) {
    gld16(aP0 ? aP0 + k0 : zp, &As[aL0]);
    gld16(aP1 ? aP1 + k0 : zp, &As[aL1]);
    if (NT == 3 && wave == 0) gld16(aP2 ? aP2 + k0 : zp, &As[aL2]);
#pragma unroll
    for (int i = 0; i < NT; ++i) gld16(bP[i] + k0, &Bs[bL[i]]);
    __syncthreads();

#pragma unroll
    for (int tap = 0; tap < NT; ++tap) {
      const int dlt = tap - ((NT == 3) ? 1 : 0);
      short8 af[4], bfr[4];
#pragma unroll
      for (int i = 0; i < 4; ++i) {
        af[i] = *(const short8*)&As[(wrow * 64 + i * 16 + fm + H + dlt) * 32 + swzA[tap]];
        if (NT == 3 && !mv[tap][i]) af[i] = zero8;
      }
#pragma unroll
      for (int j = 0; j < 4; ++j)
        bfr[j] = *(const short8*)&Bs[(tap * BN + wcol * 64 + j * 16 + fm) * 32 + swzB];
#pragma unroll
      for (int i = 0; i < 4; ++i)
#pragma unroll
        for (int j = 0; j < 4; ++j)
          acc[i][j] = __builtin_amdgcn_mfma_f32_16x16x32_bf16(af[i], bfr[j], acc[i][j], 0, 0, 0);
    }
    __syncthreads();
  }

  const int rbase = bm0 + wrow * 64 + ((lane >> 4) << 2);
  const int cbase = bn0 + wcol * 64 + fm;
#pragma unroll
  for (int j = 0; j < 4; ++j) {
    int col = cbase + j * 16;
    float bv = bias ? bias[col] : 0.f;
#pragma unroll
    for (int i = 0; i < 4; ++i) {
#pragma unroll
      for (int r = 0; r < 4; ++r) {
        int row = rbase + i * 16 + r;
        float v = acc[i][j][r] + bv;
        if (RELU) v = fmaxf(v, 0.f);
        Cm[(long)row * ldc + col] = f2bf(v);
      }
    }
  }
}

// ===========================================================================
// attn_k: fused flash attention. Block = 8 waves, 128 q-rows per block,
// grid (S/128, CB*CH). Computes S^T = K@Q^T per 64-kv tile (M=kv, N=q so the
// softmax axis is the C-frag ROW dim; per-q stats live on lane&15), online
// softmax, P->LDS (wave-private), O += P@V^T. V^T from vt buffer.
// Output O (q x 64) written to ctx[q*CD + h*64 + dh] (ctx = x1, NOT the qkv
// Q slice -- other blocks still read Q).
// ===========================================================================
__global__ __launch_bounds__(512)
void attn_k(const u16* __restrict__ qkv, const u16* __restrict__ vt,
            u16* __restrict__ ctx, const int* __restrict__ lens, int S)
{
  __shared__ u16 Ks[2][64 * 32];    // [kstep][kv][32 dh] swizzled granules
  __shared__ u16 Vts[2][64 * 32];   // [kstep][dh][32 kv] swizzled granules
  __shared__ u16 Ps[8][16][80];     // per-wave P tile [q16][kv64] (+pad)

  const int t = threadIdx.x, lane = t & 63, w = t >> 6;
  const int bh = blockIdx.y, b = bh >> 3, h = bh & 7;
  const int q0 = blockIdx.x * 128;
  const int len = lens[b];
  const int fm = lane & 15, quad = lane >> 4;
  const int swz8 = ((quad ^ ((fm >> 1) & 3)) << 3);
  const int rsub = lane >> 2;
  const int g8 = (((lane & 3) ^ ((lane >> 3) & 3)) << 3);

  // Q B-frags in registers: B[n=q=fm][k=dh], k-step 32
  const int qrow = q0 + w * 16 + fm;
  short8 bq[2];
  bq[0] = *(const short8*)&qkv[(long)(b * S + qrow) * CQKV + h * 64 + quad * 8];
  bq[1] = *(const short8*)&qkv[(long)(b * S + qrow) * CQKV + h * 64 + 32 + quad * 8];

  // staging assignment: wave w stages K chunk (ks=w&1, rows (w>>1)*16) + same Vt chunk
  const int ksW = w & 1, rg = (w >> 1) & 3;
  const u16* kBase = qkv + ((long)b * S + rg * 16 + rsub) * CQKV + CD + h * 64 + ksW * 32 + g8;
  const u16* vBase = vt + ((long)bh * 64 + rg * 16 + rsub) * S + ksW * 32 + g8;
  u16* kDst = &Ks[ksW][rg * 512];
  u16* vDst = &Vts[ksW][rg * 512];

  floatx4 acc_o[4];
#pragma unroll
  for (int j = 0; j < 4; ++j) acc_o[j] = (floatx4){0.f, 0.f, 0.f, 0.f};
  float m = -1e30f, l = 0.f;

  for (int kv0 = 0; kv0 < S; kv0 += 64) {
    __syncthreads();                      // previous-iter tile reads complete
    gld16(kBase + (long)kv0 * CQKV, kDst);
    gld16(vBase + kv0, vDst);
    __syncthreads();                      // staging visible (compiler drains vmcnt)

    // ---- S^T tile: M=kv 64 (4 frags), N=q 16, K=dh 64 (2 steps)
    floatx4 sa[4];
#pragma unroll
    for (int i = 0; i < 4; ++i) sa[i] = (floatx4){0.f, 0.f, 0.f, 0.f};
#pragma unroll
    for (int ks = 0; ks < 2; ++ks) {
#pragma unroll
      for (int mi = 0; mi < 4; ++mi) {
        short8 ak = *(const short8*)&Ks[ks][(mi * 16 + fm) * 32 + swz8];
        sa[mi] = __builtin_amdgcn_mfma_f32_16x16x32_bf16(ak, bq[ks], sa[mi], 0, 0, 0);
      }
    }

    // ---- online softmax (per q-row = per lane&15; kv on rows quad*4+r+mi*16)
    float p[4][4], tm = -1e30f;
#pragma unroll
    for (int mi = 0; mi < 4; ++mi)
#pragma unroll
      for (int r = 0; r < 4; ++r) {
        int kvg = kv0 + mi * 16 + quad * 4 + r;
        float v = (kvg <= len) ? sa[mi][r] * 0.125f : -1e30f;
        p[mi][r] = v; tm = fmaxf(tm, v);
      }
    tm = fmaxf(tm, __shfl_xor(tm, 16));
    tm = fmaxf(tm, __shfl_xor(tm, 32));
    const float mnew = fmaxf(m, tm);
    const float al = __expf(m - mnew);
    float ts = 0.f;
#pragma unroll
    for (int mi = 0; mi < 4; ++mi)
#pragma unroll
      for (int r = 0; r < 4; ++r) { float e = __expf(p[mi][r] - mnew); p[mi][r] = e; ts += e; }
    ts += __shfl_xor(ts, 16);
    ts += __shfl_xor(ts, 32);
    l = l * al + ts; m = mnew;
    float al4[4];
#pragma unroll
    for (int r = 0; r < 4; ++r) al4[r] = __shfl(al, ((lane >> 4) << 2) + r, 64);
#pragma unroll
    for (int j = 0; j < 4; ++j)
#pragma unroll
      for (int r = 0; r < 4; ++r) acc_o[j][r] *= al4[r];

    // ---- P -> LDS (wave-private): Ps[w][q=fm][kv = mi*16+quad*4+r]
#pragma unroll
    for (int mi = 0; mi < 4; ++mi) {
      unsigned u01 = (unsigned)f2bf(p[mi][0]) | ((unsigned)f2bf(p[mi][1]) << 16);
      unsigned u23 = (unsigned)f2bf(p[mi][2]) | ((unsigned)f2bf(p[mi][3]) << 16);
      *(uint2*)&Ps[w][fm][mi * 16 + quad * 4] = make_uint2(u01, u23);
    }

    // ---- O += P @ V: M=q 16, N=dh 64 (4 frags), K=kv 64 (2 steps)
#pragma unroll
    for (int ks = 0; ks < 2; ++ks) {
      short8 ap = *(const short8*)&Ps[w][fm][ks * 32 + quad * 8];
#pragma unroll
      for (int nj = 0; nj < 4; ++nj) {
        short8 bv = *(const short8*)&Vts[ks][(nj * 16 + fm) * 32 + swz8];
        acc_o[nj] = __builtin_amdgcn_mfma_f32_16x16x32_bf16(ap, bv, acc_o[nj], 0, 0, 0);
      }
    }
  }

  // ---- epilogue: O[q][dh] / l
  float li4[4];
#pragma unroll
  for (int r = 0; r < 4; ++r) li4[r] = 1.f / __shfl(l, ((lane >> 4) << 2) + r, 64);
#pragma unroll
  for (int nj = 0; nj < 4; ++nj)
#pragma unroll
    for (int r = 0; r < 4; ++r) {
      int qr = q0 + w * 16 + quad * 4 + r;
      ctx[(long)(b * S + qr) * CD + h * 64 + nj * 16 + fm] = f2bf(acc_o[nj][r] * li4[r]);
    }
}

// ---------------------------------------------------------------------------
// Final-projection GEMM (N=80), f32 transposed store to d_out (R3 kernel).
// ---------------------------------------------------------------------------
template<int BM, int BN>
__global__ __launch_bounds__(256)
void gemmF_k(const u16* __restrict__ A, const u16* __restrict__ Bm,
             float* __restrict__ Cm, const float* __restrict__ bias,
             int M, int N, int K, int lda, int ldb,
             const u16* __restrict__ zp)
{
  __shared__ u16 As[BM * 32];
  __shared__ u16 Bs[BN * 32];

  const int t = threadIdx.x;
  const int lane = t & 63;
  const int wave = t >> 6;
  constexpr int WCOLS = BN / 64;
  const int wrow = wave / WCOLS;
  const int wcol = wave % WCOLS;
  const int bn0 = blockIdx.x * BN;
  const int bm0 = blockIdx.y * BM;

  floatx4 acc[4][4];
#pragma unroll
  for (int i = 0; i < 4; ++i)
#pragma unroll
    for (int j = 0; j < 4; ++j) acc[i][j] = (floatx4){0.f, 0.f, 0.f, 0.f};

  const int rsub = lane >> 2;
  const int g8 = (((lane & 3) ^ ((lane >> 3) & 3)) << 3);
  constexpr int PA = BM / 64, PB = BN / 64;

  const int q = lane >> 4, fm = lane & 15;
  const int swz8 = ((q ^ ((fm >> 1) & 3)) << 3);

  const u16* aP[PA]; const u16* bP[PB];
#pragma unroll
  for (int p = 0; p < PA; ++p)
    aP[p] = A + (long)(bm0 + p * 64 + wave * 16 + rsub) * lda + g8;
#pragma unroll
  for (int p = 0; p < PB; ++p) {
    int r = p * 64 + wave * 16 + rsub;
    bP[p] = ((bn0 + r) < N) ? (Bm + (long)(bn0 + r) * ldb + g8) : nullptr;
  }

  for (int k0 = 0; k0 < K; k0 += 32) {
#pragma unroll
    for (int p = 0; p < PA; ++p)
      gld16(aP[p] + k0, &As[(p * 64 + wave * 16) * 32]);
#pragma unroll
    for (int p = 0; p < PB; ++p)
      gld16(bP[p] ? bP[p] + k0 : zp, &Bs[(p * 64 + wave * 16) * 32]);
    __syncthreads();

    short8 af[4], bfr[4];
#pragma unroll
    for (int i = 0; i < 4; ++i)
      af[i] = *(const short8*)&As[(wrow * 64 + i * 16 + fm) * 32 + swz8];
#pragma unroll
    for (int j = 0; j < 4; ++j)
      bfr[j] = *(const short8*)&Bs[(wcol * 64 + j * 16 + fm) * 32 + swz8];
#pragma unroll
    for (int i = 0; i < 4; ++i)
#pragma unroll
      for (int j = 0; j < 4; ++j)
        acc[i][j] = __builtin_amdgcn_mfma_f32_16x16x32_bf16(af[i], bfr[j], acc[i][j], 0, 0, 0);
    __syncthreads();
  }

  const int rbase = bm0 + wrow * 64 + ((lane >> 4) << 2);
  const int cbase = bn0 + wcol * 64 + (lane & 15);
#pragma unroll
  for (int j = 0; j < 4; ++j) {
    int col = cbase + j * 16;
    if (col >= N) continue;
    float bv = bias ? bias[col] : 0.f;
#pragma unroll
    for (int i = 0; i < 4; ++i) {
#pragma unroll
      for (int r = 0; r < 4; ++r) {
        int row = rbase + i * 16 + r;
        // row = b*1024 + f ; out[b][col][f]
        Cm[((long)(row >> 10) * COUT + col) * CMEL + (row & 1023)] = acc[i][j][r] + bv;
      }
    }
  }
}

// ---------------------------------------------------------------------------
// W [tap][K][N] f32 -> WT [tap][N][K] bf16 (LDS-tiled 32x32 transpose)
__global__ void cvt_t_k(const float* __restrict__ src, u16* __restrict__ dst, int K, int N)
{
  const int tap = blockIdx.z;
  const int n0 = blockIdx.x * 32, k0 = blockIdx.y * 32;
  __shared__ float tile[32][33];
  const int t = threadIdx.x;
  const int c = t & 31, rr = t >> 5;
  const float* s = src + (long)tap * K * N;
  u16* d = dst + (long)tap * K * N;
#pragma unroll
  for (int i = 0; i < 4; ++i) {
    int k = k0 + rr + i * 8, n = n0 + c;
    tile[rr + i * 8][c] = (k < K && n < N) ? s[(long)k * N + n] : 0.f;
  }
  __syncthreads();
#pragma unroll
  for (int i = 0; i < 4; ++i) {
    int n = n0 + rr + i * 8, k = k0 + c;
    if (n < N && k < K) d[(long)n * K + k] = f2bf(tile[c][rr + i * 8]);
  }
}

// vt[(b*CH+h)*64 + d][S] = qkv[(b*S+s)*CQKV + 2*CD + h*64 + d]
__global__ void vtr_k(const u16* __restrict__ qkv, u16* __restrict__ vt, int S)
{
  const int s0 = blockIdx.x * 64;
  const int bh = blockIdx.y;
  const int b = bh >> 3, h = bh & 7;
  __shared__ u16 tile[64][65];
  const int t = threadIdx.x;
  const int wave = t >> 6, lane = t & 63;
#pragma unroll
  for (int i = 0; i < 16; ++i) {
    int sl = wave * 16 + i;
    tile[sl][lane] = qkv[(long)(b * S + s0 + sl) * CQKV + 2 * CD + h * 64 + lane];
  }
  __syncthreads();
  const int dl = t >> 2, sc4 = (t & 3) << 4;
  u16* dstp = vt + ((long)bh * 64 + dl) * S + s0 + sc4;
  short8 v0, v1;
#pragma unroll
  for (int j = 0; j < 8; ++j) { v0[j] = (short)tile[sc4 + j][dl]; v1[j] = (short)tile[sc4 + 8 + j][dl]; }
  *(short8*)dstp = v0;
  *(short8*)(dstp + 8) = v1;
}

__global__ void fill_k(float* __restrict__ o, int n, float v)
{
  int i = blockIdx.x * 256 + threadIdx.x;
  if (i < n) o[i] = v;
}

// x[b,t,:] = bf16( 2*emb[tok] + pos[b] )   (reference quirk: pos indexed by BATCH b)
__global__ void embed_k(const int* __restrict__ tok, const float* __restrict__ emb,
                        u16* __restrict__ X)
{
  const long idx = (long)blockIdx.x * 256 + threadIdx.x;
  const int d = (int)(idx & (CD - 1));
  const int m = (int)(idx >> 9);
  const int b = m >> 8;
  const float e = emb[(long)tok[m] * CD + d];
  const int i2 = d >> 1;
  const float den = __expf(-(float)(2 * i2) * (9.210340371976184f / 512.f));
  const float ang = (float)b * den;
  const float p = (d & 1) ? __cosf(ang) : __sinf(ang);
  X[idx] = f2bf(2.f * e + p);
}

// O = LN(X + Y) * g + b ; one block per row, D=512, f32 stats
__global__ void ln_res_k(const u16* __restrict__ X, const u16* __restrict__ Y,
                         const float* __restrict__ g, const float* __restrict__ bta,
                         u16* __restrict__ O)
{
  const int m = blockIdx.x, t = threadIdx.x;
  const long base = (long)m * CD;
  float v0 = bf2f(X[base + t]) + bf2f(Y[base + t]);
  float v1 = bf2f(X[base + t + 256]) + bf2f(Y[base + t + 256]);
  __shared__ float red[256];
  red[t] = v0 + v1; __syncthreads();
  for (int s = 128; s > 0; s >>= 1) { if (t < s) red[t] += red[t + s]; __syncthreads(); }
  const float mean = red[0] * (1.f / 512.f);
  __syncthreads();
  const float d0 = v0 - mean, d1 = v1 - mean;
  red[t] = d0 * d0 + d1 * d1; __syncthreads();
  for (int s = 128; s > 0; s >>= 1) { if (t < s) red[t] += red[t + s]; __syncthreads(); }
  const float rstd = rsqrtf(red[0] * (1.f / 512.f) + 1e-5f);
  O[base + t]       = f2bf(d0 * rstd * g[t] + bta[t]);
  O[base + t + 256] = f2bf(d1 * rstd * g[t + 256] + bta[t + 256]);
}

__global__ void cumsum_k(const int* __restrict__ dur, int* __restrict__ cums)
{
  int b = threadIdx.x;
  if (b < CB) {
    int s = 0;
    for (int t = 0; t < CT; ++t) { s += dur[b * CT + t]; cums[b * CT + t] = s; }
  }
}

__global__ void regulate_k(const u16* __restrict__ xe, const int* __restrict__ cums,
                           const int* __restrict__ mlen, u16* __restrict__ xd)
{
  const int m = blockIdx.x;
  const int b = m >> 10, f = m & (CMEL - 1);
  int lo = 0, hi = CT;
  while (lo < hi) { int mid = (lo + hi) >> 1; if (cums[b * CT + mid] <= f) lo = mid + 1; else hi = mid; }
  const int idx = min(lo, CT - 1);
  const bool keep = (f <= mlen[b]);
  const u16* src = xe + ((long)b * CT + idx) * CD;
  u16* dst = xd + (long)m * CD;
  const int t = threadIdx.x;
  dst[t]       = keep ? src[t] : (u16)0;
  dst[t + 256] = keep ? src[t + 256] : (u16)0;
}

// ---------------------------------------------------------------------------
extern "C" void kernel_launch(void* const* d_in, const int* in_sizes, int n_in,
                              void* d_out, int out_size, void* d_ws, size_t ws_size,
                              hipStream_t stream)
{
  (void)in_sizes; (void)n_in;
  const int*   tokens = (const int*)d_in[0];
  const int*   tlen   = (const int*)d_in[1];
  const int*   mlen   = (const int*)d_in[2];
  const int*   dur    = (const int*)d_in[3];
  const float* emb    = (const float*)d_in[5];
  const float* ew[12]; const float* dw[12];
  for (int i = 0; i < 12; ++i) { ew[i] = (const float*)d_in[6 + i]; dw[i] = (const float*)d_in[18 + i]; }
  const float* out_w = (const float*)d_in[30];
  const float* out_b = (const float*)d_in[31];

  const int Me = CB * CT;       // 4096
  const int Md = CB * CMEL;     // 16384

  // ---- workspace (lifetime-aliased; no score buffer anymore) ---------------
  const size_t SZ_ZP   = 256;
  const size_t SZ_WBUF = (size_t)3 * CD * CINTER * 2;
  const size_t SZ_XE   = (size_t)Me * CD * 2;
  const size_t SZ_XD   = (size_t)Md * CD * 2;     // x, x1(ctx), yb(vt)
  const size_t SZ_QKV  = (size_t)Md * CQKV * 2;   // 50.3 MB
  const size_t SZ_HB   = (size_t)Md * CINTER * 2; // 67.1 MB
  const size_t SZ_CUMS = (size_t)CB * CT * 4;
  auto al = [](size_t b) { return (b + 255) & ~(size_t)255; };
  size_t U = al(SZ_QKV) > al(SZ_HB) ? al(SZ_QKV) : al(SZ_HB);
  size_t total = al(SZ_ZP) + al(SZ_WBUF) + al(SZ_XE) + 3 * al(SZ_XD) + U + al(SZ_CUMS);
  if (total > ws_size) {
    fill_k<<<dim3((unsigned)((out_size + 255) / 256)), dim3(256), 0, stream>>>(
        (float*)d_out, out_size, 1000.0f);
    return;
  }

  char* p = (char*)d_ws;
  auto take = [&](size_t bytes) { char* r = p; p += al(bytes); return r; };
  u16*  zp   = (u16*)take(SZ_ZP);
  u16*  wbuf = (u16*)take(SZ_WBUF);
  u16*  xe   = (u16*)take(SZ_XE);
  u16*  xd   = (u16*)take(SZ_XD);
  u16*  x1   = (u16*)take(SZ_XD);   // also ctx during attention
  u16*  yb   = (u16*)take(SZ_XD);   // also vt during attention
  char* U0   = take(U);
  u16*  qkvB = (u16*)U0;
  u16*  hb   = (u16*)U0;
  int* cums = (int*)take(SZ_CUMS);

  hipMemsetAsync(zp, 0, SZ_ZP, stream);

  auto cvtT = [&](const float* s, u16* d, int K, int N, int taps) {
    cvt_t_k<<<dim3((unsigned)((N + 31) / 32), (unsigned)((K + 31) / 32), (unsigned)taps),
              dim3(256), 0, stream>>>(s, d, K, N);
  };

  embed_k<<<dim3((unsigned)((long)Me * CD / 256)), dim3(256), 0, stream>>>(tokens, emb, xe);

  auto run_stack = [&](u16* x, int S, int M, const int* lens, const float* const* W) {
    u16* vt = yb;
    for (int l = 0; l < CL; ++l) {
      // qkv = x @ Wqkv + b
      cvtT(W[0] + (long)l * CD * CQKV, wbuf, CD, CQKV, 1);
      gemm2_k<1, false><<<dim3(CQKV / 128, M / 256), dim3(512), 0, stream>>>(
          x, wbuf, qkvB, W[1] + l * CQKV, M, CQKV, CD, CD, CD, CQKV, S - 1, 0, zp);
      // V^T
      vtr_k<<<dim3((unsigned)(S / 64), (unsigned)(CB * CH)), dim3(256), 0, stream>>>(qkvB, vt, S);
      // fused attention -> ctx (= x1)
      attn_k<<<dim3((unsigned)(S / 128), (unsigned)(CB * CH)), dim3(512), 0, stream>>>(
          qkvB, vt, x1, lens, S);
      // proj: ctx @ Wo + bo -> yb
      cvtT(W[2] + (long)l * CD * CD, wbuf, CD, CD, 1);
      gemm2_k<1, false><<<dim3(CD / 128, M / 256), dim3(512), 0, stream>>>(
          x1, wbuf, yb, W[3] + l * CD, M, CD, CD, CD, CD, CD, S - 1, 0, zp);
      ln_res_k<<<dim3((unsigned)M), dim3(256), 0, stream>>>(x, yb, W[4] + l * CD, W[5] + l * CD, x1);
      // conv1 (3-tap) + relu
      cvtT(W[6] + (long)l * 3 * CD * CINTER, wbuf, CD, CINTER, 3);
      gemm2_k<3, true><<<dim3(CINTER / 128, M / 256), dim3(512), 0, stream>>>(
          x1, wbuf, hb, W[7] + l * CINTER, M, CINTER, CD, CD, CD, CINTER,
          S - 1, (long)CD * CINTER, zp);
      // conv2 (3-tap)
      cvtT(W[8] + (long)l * 3 * CINTER * CD, wbuf, CINTER, CD, 3);
      gemm2_k<3, false><<<dim3(CD / 128, M / 256), dim3(512), 0, stream>>>(
          hb, wbuf, yb, W[9] + l * CD, M, CD, CINTER, CINTER, CINTER, CD,
          S - 1, (long)CINTER * CD, zp);
      ln_res_k<<<dim3((unsigned)M), dim3(256), 0, stream>>>(x1, yb, W[10] + l * CD, W[11] + l * CD, x);
    }
  };

  run_stack(xe, CT, Me, tlen, ew);

  cumsum_k<<<dim3(1), dim3(64), 0, stream>>>(dur, cums);
  regulate_k<<<dim3((unsigned)(CB * CMEL)), dim3(256), 0, stream>>>(xe, cums, mlen, xd);

  run_stack(xd, CMEL, Md, mlen, dw);

  // final projection, transposed f32 store straight to d_out
  cvtT(out_w, wbuf, CD, COUT, 1);
  gemmF_k<128, 128><<<dim3(1, Md / 128), dim3(256), 0, stream>>>(
      xd, wbuf, (float*)d_out, out_b, Md, COUT, CD, CD, CD, zp);
}

// Round 6
// 2679.419 us; speedup vs baseline: 4.3010x; 1.0789x over previous
//
#include <hip/hip_runtime.h>

typedef unsigned short u16;
typedef short short8 __attribute__((ext_vector_type(8)));
typedef float floatx4 __attribute__((ext_vector_type(4)));

static constexpr int CB = 16, CT = 256, CMEL = 1024, CD = 512, CH = 8, CDH = 64, CL = 4;
static constexpr int CINTER = 2048, COUT = 80;
static constexpr int CQKV = 3 * CH * CDH;   // 1536

static __device__ __forceinline__ float bf2f(u16 u) {
  union { unsigned u; float f; } v; v.u = ((unsigned)u) << 16; return v.f;
}
static __device__ __forceinline__ u16 f2bf(float f) {  // RNE; inputs finite
  union { float f; unsigned u; } v; v.f = f;
  unsigned r = v.u + 0x7fffu + ((v.u >> 16) & 1u);
  return (u16)(r >> 16);
}

// async global->LDS, 16B per lane; LDS dest = wave-uniform base + lane*16 (m104/m108)
static __device__ __forceinline__ void gld16(const u16* g, u16* lds) {
  __builtin_amdgcn_global_load_lds((const __attribute__((address_space(1))) void*)g,
                                   (__attribute__((address_space(3))) void*)lds, 16, 0, 0);
}

// ===========================================================================
// gemm2_k: 128x128-tile, 4-wave (256 thr) bf16 MFMA GEMM with folded conv taps.
// R6: retiled from 256x128/8-wave per m112 evidence (128^2 = 912 TF beats
// larger tiles on the 2-barrier structure; shorter barrier convoys, 4 blk/CU).
// A: M x K row-major. B: [tap][N][K]. C: M x N bf16. NT=1 plain / NT=3 conv.
// A staged once with +-8 halo (144 rows, 9 chunks). Granule-XOR swizzle; tap
// validity via fragment zeroing (S power of two, Sm1 mask).
// ===========================================================================
template<int NT, bool RELU>
__global__ __launch_bounds__(256)
void gemm2_k(const u16* __restrict__ A, const u16* __restrict__ Bm,
             u16* __restrict__ Cm, const float* __restrict__ bias,
             int M, int N, int K, int lda, int ldb, int ldc,
             int Sm1, long tapStrideB, const u16* __restrict__ zp)
{
  constexpr int BM = 128, BN = 128;
  constexpr int H = (NT == 3) ? 8 : 0;
  constexpr int AR = BM + 2 * H;           // 144 or 128
  __shared__ u16 As[AR * 32];
  __shared__ u16 Bs[NT * BN * 32];

  const int t = threadIdx.x;
  const int lane = t & 63;
  const int wave = t >> 6;                 // 0..3
  const int wrow = wave >> 1;              // 0..1
  const int wcol = wave & 1;               // 0..1
  const int bn0 = blockIdx.x * BN;
  const int bm0 = blockIdx.y * BM;

  floatx4 acc[4][4];
#pragma unroll
  for (int i = 0; i < 4; ++i)
#pragma unroll
    for (int j = 0; j < 4; ++j) acc[i][j] = (floatx4){0.f, 0.f, 0.f, 0.f};

  const int rsub = lane >> 2;
  const int g8 = (((lane & 3) ^ ((lane >> 3) & 3)) << 3);

  // ---- A chunk pointers: chunks {wave, wave+4} (+ chunk 8 by wave 0, NT=3)
  const u16* aP0; const u16* aP1; const u16* aP2 = nullptr;
  {
    int gg0 = bm0 - H + wave * 16 + rsub;
    int gg1 = bm0 - H + (wave + 4) * 16 + rsub;
    aP0 = ((NT == 1) || ((unsigned)gg0 < (unsigned)M)) ? A + (long)gg0 * lda + g8 : nullptr;
    aP1 = ((NT == 1) || ((unsigned)gg1 < (unsigned)M)) ? A + (long)gg1 * lda + g8 : nullptr;
    if (NT == 3 && wave == 0) {
      int gg2 = bm0 - H + 128 + rsub;      // chunk 8
      aP2 = ((unsigned)gg2 < (unsigned)M) ? A + (long)gg2 * lda + g8 : nullptr;
    }
  }
  const int aL0 = wave * 512, aL1 = (wave + 4) * 512, aL2 = 8 * 512;

  // ---- B chunk pointers: per tap, chunks {wave, wave+4}
  const u16* bP[NT][2]; int bL[NT][2];
#pragma unroll
  for (int i = 0; i < NT; ++i)
#pragma unroll
    for (int j = 0; j < 2; ++j) {
      int r = (wave + j * 4) * 16 + rsub;
      bP[i][j] = Bm + (long)i * tapStrideB + (long)(bn0 + r) * ldb + g8;
      bL[i][j] = (i * BN + (wave + j * 4) * 16) * 32;
    }

  const int q = lane >> 4, fm = lane & 15;
  const int swzB = (q ^ ((fm >> 1) & 3)) << 3;
  int swzA[NT];
  bool mv[NT][4];
#pragma unroll
  for (int tap = 0; tap < NT; ++tap) {
    const int dlt = tap - ((NT == 3) ? 1 : 0);
    swzA[tap] = (q ^ ((((H + dlt + fm) & 15) >> 1) & 3)) << 3;
#pragma unroll
    for (int i = 0; i < 4; ++i) {
      int s = (bm0 + wrow * 64 + i * 16 + fm) & Sm1;
      mv[tap][i] = ((unsigned)(s + dlt) <= (unsigned)Sm1);
    }
  }
  const short8 zero8 = {};

  for (int k0 = 0; k0 < K; k0 += 32) {
    gld16(aP0 ? aP0 + k0 : zp, &As[aL0]);
    gld16(aP1 ? aP1 + k0 : zp, &As[aL1]);
    if (NT == 3 && wave == 0) gld16(aP2 ? aP2 + k0 : zp, &As[aL2]);
#pragma unroll
    for (int i = 0; i < NT; ++i)
#pragma unroll
      for (int j = 0; j < 2; ++j) gld16(bP[i][j] + k0, &Bs[bL[i][j]]);
    __syncthreads();

#pragma unroll
    for (int tap = 0; tap < NT; ++tap) {
      const int dlt = tap - ((NT == 3) ? 1 : 0);
      short8 af[4], bfr[4];
#pragma unroll
      for (int i = 0; i < 4; ++i) {
        af[i] = *(const short8*)&As[(wrow * 64 + i * 16 + fm + H + dlt) * 32 + swzA[tap]];
        if (NT == 3 && !mv[tap][i]) af[i] = zero8;
      }
#pragma unroll
      for (int j = 0; j < 4; ++j)
        bfr[j] = *(const short8*)&Bs[(tap * BN + wcol * 64 + j * 16 + fm) * 32 + swzB];
#pragma unroll
      for (int i = 0; i < 4; ++i)
#pragma unroll
        for (int j = 0; j < 4; ++j)
          acc[i][j] = __builtin_amdgcn_mfma_f32_16x16x32_bf16(af[i], bfr[j], acc[i][j], 0, 0, 0);
    }
    __syncthreads();
  }

  const int rbase = bm0 + wrow * 64 + ((lane >> 4) << 2);
  const int cbase = bn0 + wcol * 64 + fm;
#pragma unroll
  for (int j = 0; j < 4; ++j) {
    int col = cbase + j * 16;              // N multiple of 128 for all gemm2 uses
    float bv = bias ? bias[col] : 0.f;
#pragma unroll
    for (int i = 0; i < 4; ++i) {
#pragma unroll
      for (int r = 0; r < 4; ++r) {
        int row = rbase + i * 16 + r;
        float v = acc[i][j][r] + bv;
        if (RELU) v = fmaxf(v, 0.f);
        Cm[(long)row * ldc + col] = f2bf(v);
      }
    }
  }
}

// ===========================================================================
// attn_k: fused flash attention, R6: kv-tile widened 64 -> 128 (half the
// barriers, half the softmax reductions per kv). Block = 8 waves, 128 q-rows.
// S^T = K@Q^T (M=kv so softmax axis is the C-frag row dim), online softmax,
// P->LDS (wave-private), O += P@V^T.
// ===========================================================================
__global__ __launch_bounds__(512)
void attn_k(const u16* __restrict__ qkv, const u16* __restrict__ vt,
            u16* __restrict__ ctx, const int* __restrict__ lens, int S)
{
  __shared__ __attribute__((aligned(16))) u16 Ks[2][128 * 32];   // [dh-step][kv][32 dh]
  __shared__ __attribute__((aligned(16))) u16 Vts[4][64 * 32];   // [kv-step][dh][32 kv]
  __shared__ __attribute__((aligned(16))) u16 Ps[8][16][136];    // per-wave P [q16][kv128]+pad

  const int t = threadIdx.x, lane = t & 63, w = t >> 6;
  const int bh = blockIdx.y, b = bh >> 3, h = bh & 7;
  const int q0 = blockIdx.x * 128;
  const int len = lens[b];
  const int fm = lane & 15, quad = lane >> 4;
  const int swz8 = ((quad ^ ((fm >> 1) & 3)) << 3);
  const int rsub = lane >> 2;
  const int g8 = (((lane & 3) ^ ((lane >> 3) & 3)) << 3);

  // Q B-frags in registers: B[n=q=fm][k=dh]
  const int qrow = q0 + w * 16 + fm;
  short8 bq[2];
  bq[0] = *(const short8*)&qkv[(long)(b * S + qrow) * CQKV + h * 64 + quad * 8];
  bq[1] = *(const short8*)&qkv[(long)(b * S + qrow) * CQKV + h * 64 + 32 + quad * 8];

  // K staging: 16 chunks (ks in {0,1} x rg in 0..7); wave w takes (w&1, w>>1) and (w&1, w>>1+4)
  const int ksW = w & 1, rgA = w >> 1, rgB = (w >> 1) + 4;
  const u16* kBaseA = qkv + ((long)b * S + rgA * 16 + rsub) * CQKV + CD + h * 64 + ksW * 32 + g8;
  const u16* kBaseB = qkv + ((long)b * S + rgB * 16 + rsub) * CQKV + CD + h * 64 + ksW * 32 + g8;
  u16* kDstA = &Ks[ksW][rgA * 512];
  u16* kDstB = &Ks[ksW][rgB * 512];
  // Vt staging: 16 chunks c = kvs*4 + dhc; wave w takes c = 2w, 2w+1
  const int kvs0 = (2 * w) >> 2, dhc0 = (2 * w) & 3;
  const int kvs1 = (2 * w + 1) >> 2, dhc1 = (2 * w + 1) & 3;
  const u16* vBase0 = vt + ((long)bh * 64 + dhc0 * 16 + rsub) * S + kvs0 * 32 + g8;
  const u16* vBase1 = vt + ((long)bh * 64 + dhc1 * 16 + rsub) * S + kvs1 * 32 + g8;
  u16* vDst0 = &Vts[kvs0][dhc0 * 512];
  u16* vDst1 = &Vts[kvs1][dhc1 * 512];

  floatx4 acc_o[4];
#pragma unroll
  for (int j = 0; j < 4; ++j) acc_o[j] = (floatx4){0.f, 0.f, 0.f, 0.f};
  float m = -1e30f, l = 0.f;

  for (int kv0 = 0; kv0 < S; kv0 += 128) {
    __syncthreads();                      // previous-iter tile reads complete
    gld16(kBaseA + (long)kv0 * CQKV, kDstA);
    gld16(kBaseB + (long)kv0 * CQKV, kDstB);
    gld16(vBase0 + kv0, vDst0);
    gld16(vBase1 + kv0, vDst1);
    __syncthreads();                      // staging visible

    // ---- S^T tile: M=kv 128 (8 frags), N=q 16, K=dh 64 (2 steps)
    floatx4 sa[8];
#pragma unroll
    for (int i = 0; i < 8; ++i) sa[i] = (floatx4){0.f, 0.f, 0.f, 0.f};
#pragma unroll
    for (int ks = 0; ks < 2; ++ks) {
#pragma unroll
      for (int mi = 0; mi < 8; ++mi) {
        short8 ak = *(const short8*)&Ks[ks][(mi * 16 + fm) * 32 + swz8];
        sa[mi] = __builtin_amdgcn_mfma_f32_16x16x32_bf16(ak, bq[ks], sa[mi], 0, 0, 0);
      }
    }

    // ---- online softmax (per q-row = lane&15; kv rows = mi*16 + quad*4 + r)
    float p[8][4], tm = -1e30f;
#pragma unroll
    for (int mi = 0; mi < 8; ++mi)
#pragma unroll
      for (int r = 0; r < 4; ++r) {
        int kvg = kv0 + mi * 16 + quad * 4 + r;
        float v = (kvg <= len) ? sa[mi][r] * 0.125f : -1e30f;
        p[mi][r] = v; tm = fmaxf(tm, v);
      }
    tm = fmaxf(tm, __shfl_xor(tm, 16));
    tm = fmaxf(tm, __shfl_xor(tm, 32));
    const float mnew = fmaxf(m, tm);
    const float al = __expf(m - mnew);
    float ts = 0.f;
#pragma unroll
    for (int mi = 0; mi < 8; ++mi)
#pragma unroll
      for (int r = 0; r < 4; ++r) { float e = __expf(p[mi][r] - mnew); p[mi][r] = e; ts += e; }
    ts += __shfl_xor(ts, 16);
    ts += __shfl_xor(ts, 32);
    l = l * al + ts; m = mnew;
    float al4[4];
#pragma unroll
    for (int r = 0; r < 4; ++r) al4[r] = __shfl(al, ((lane >> 4) << 2) + r, 64);
#pragma unroll
    for (int j = 0; j < 4; ++j)
#pragma unroll
      for (int r = 0; r < 4; ++r) acc_o[j][r] *= al4[r];

    // ---- P -> LDS (wave-private): Ps[w][q=fm][kv = mi*16+quad*4+r]
#pragma unroll
    for (int mi = 0; mi < 8; ++mi) {
      unsigned u01 = (unsigned)f2bf(p[mi][0]) | ((unsigned)f2bf(p[mi][1]) << 16);
      unsigned u23 = (unsigned)f2bf(p[mi][2]) | ((unsigned)f2bf(p[mi][3]) << 16);
      *(uint2*)&Ps[w][fm][mi * 16 + quad * 4] = make_uint2(u01, u23);
    }

    // ---- O += P @ V: M=q 16, N=dh 64 (4 frags), K=kv 128 (4 steps)
#pragma unroll
    for (int kvs = 0; kvs < 4; ++kvs) {
      short8 ap = *(const short8*)&Ps[w][fm][kvs * 32 + quad * 8];
#pragma unroll
      for (int nj = 0; nj < 4; ++nj) {
        short8 bv = *(const short8*)&Vts[kvs][(nj * 16 + fm) * 32 + swz8];
        acc_o[nj] = __builtin_amdgcn_mfma_f32_16x16x32_bf16(ap, bv, acc_o[nj], 0, 0, 0);
      }
    }
  }

  // ---- epilogue: O[q][dh] / l
  float li4[4];
#pragma unroll
  for (int r = 0; r < 4; ++r) li4[r] = 1.f / __shfl(l, ((lane >> 4) << 2) + r, 64);
#pragma unroll
  for (int nj = 0; nj < 4; ++nj)
#pragma unroll
    for (int r = 0; r < 4; ++r) {
      int qr = q0 + w * 16 + quad * 4 + r;
      ctx[(long)(b * S + qr) * CD + h * 64 + nj * 16 + fm] = f2bf(acc_o[nj][r] * li4[r]);
    }
}

// ---------------------------------------------------------------------------
// Final-projection GEMM (N=80), f32 transposed store to d_out.
// ---------------------------------------------------------------------------
template<int BM, int BN>
__global__ __launch_bounds__(256)
void gemmF_k(const u16* __restrict__ A, const u16* __restrict__ Bm,
             float* __restrict__ Cm, const float* __restrict__ bias,
             int M, int N, int K, int lda, int ldb,
             const u16* __restrict__ zp)
{
  __shared__ u16 As[BM * 32];
  __shared__ u16 Bs[BN * 32];

  const int t = threadIdx.x;
  const int lane = t & 63;
  const int wave = t >> 6;
  constexpr int WCOLS = BN / 64;
  const int wrow = wave / WCOLS;
  const int wcol = wave % WCOLS;
  const int bn0 = blockIdx.x * BN;
  const int bm0 = blockIdx.y * BM;

  floatx4 acc[4][4];
#pragma unroll
  for (int i = 0; i < 4; ++i)
#pragma unroll
    for (int j = 0; j < 4; ++j) acc[i][j] = (floatx4){0.f, 0.f, 0.f, 0.f};

  const int rsub = lane >> 2;
  const int g8 = (((lane & 3) ^ ((lane >> 3) & 3)) << 3);
  constexpr int PA = BM / 64, PB = BN / 64;

  const int q = lane >> 4, fm = lane & 15;
  const int swz8 = ((q ^ ((fm >> 1) & 3)) << 3);

  const u16* aP[PA]; const u16* bP[PB];
#pragma unroll
  for (int p = 0; p < PA; ++p)
    aP[p] = A + (long)(bm0 + p * 64 + wave * 16 + rsub) * lda + g8;
#pragma unroll
  for (int p = 0; p < PB; ++p) {
    int r = p * 64 + wave * 16 + rsub;
    bP[p] = ((bn0 + r) < N) ? (Bm + (long)(bn0 + r) * ldb + g8) : nullptr;
  }

  for (int k0 = 0; k0 < K; k0 += 32) {
#pragma unroll
    for (int p = 0; p < PA; ++p)
      gld16(aP[p] + k0, &As[(p * 64 + wave * 16) * 32]);
#pragma unroll
    for (int p = 0; p < PB; ++p)
      gld16(bP[p] ? bP[p] + k0 : zp, &Bs[(p * 64 + wave * 16) * 32]);
    __syncthreads();

    short8 af[4], bfr[4];
#pragma unroll
    for (int i = 0; i < 4; ++i)
      af[i] = *(const short8*)&As[(wrow * 64 + i * 16 + fm) * 32 + swz8];
#pragma unroll
    for (int j = 0; j < 4; ++j)
      bfr[j] = *(const short8*)&Bs[(wcol * 64 + j * 16 + fm) * 32 + swz8];
#pragma unroll
    for (int i = 0; i < 4; ++i)
#pragma unroll
      for (int j = 0; j < 4; ++j)
        acc[i][j] = __builtin_amdgcn_mfma_f32_16x16x32_bf16(af[i], bfr[j], acc[i][j], 0, 0, 0);
    __syncthreads();
  }

  const int rbase = bm0 + wrow * 64 + ((lane >> 4) << 2);
  const int cbase = bn0 + wcol * 64 + (lane & 15);
#pragma unroll
  for (int j = 0; j < 4; ++j) {
    int col = cbase + j * 16;
    if (col >= N) continue;
    float bv = bias ? bias[col] : 0.f;
#pragma unroll
    for (int i = 0; i < 4; ++i) {
#pragma unroll
      for (int r = 0; r < 4; ++r) {
        int row = rbase + i * 16 + r;
        Cm[((long)(row >> 10) * COUT + col) * CMEL + (row & 1023)] = acc[i][j][r] + bv;
      }
    }
  }
}

// ---------------------------------------------------------------------------
// W [tap][K][N] f32 -> WT [tap][N][K] bf16 (LDS-tiled 32x32 transpose)
__global__ void cvt_t_k(const float* __restrict__ src, u16* __restrict__ dst, int K, int N)
{
  const int tap = blockIdx.z;
  const int n0 = blockIdx.x * 32, k0 = blockIdx.y * 32;
  __shared__ float tile[32][33];
  const int t = threadIdx.x;
  const int c = t & 31, rr = t >> 5;
  const float* s = src + (long)tap * K * N;
  u16* d = dst + (long)tap * K * N;
#pragma unroll
  for (int i = 0; i < 4; ++i) {
    int k = k0 + rr + i * 8, n = n0 + c;
    tile[rr + i * 8][c] = (k < K && n < N) ? s[(long)k * N + n] : 0.f;
  }
  __syncthreads();
#pragma unroll
  for (int i = 0; i < 4; ++i) {
    int n = n0 + rr + i * 8, k = k0 + c;
    if (n < N && k < K) d[(long)n * K + k] = f2bf(tile[c][rr + i * 8]);
  }
}

// vt[(b*CH+h)*64 + d][S] = qkv[(b*S+s)*CQKV + 2*CD + h*64 + d]
__global__ void vtr_k(const u16* __restrict__ qkv, u16* __restrict__ vt, int S)
{
  const int s0 = blockIdx.x * 64;
  const int bh = blockIdx.y;
  const int b = bh >> 3, h = bh & 7;
  __shared__ u16 tile[64][65];
  const int t = threadIdx.x;
  const int wave = t >> 6, lane = t & 63;
#pragma unroll
  for (int i = 0; i < 16; ++i) {
    int sl = wave * 16 + i;
    tile[sl][lane] = qkv[(long)(b * S + s0 + sl) * CQKV + 2 * CD + h * 64 + lane];
  }
  __syncthreads();
  const int dl = t >> 2, sc4 = (t & 3) << 4;
  u16* dstp = vt + ((long)bh * 64 + dl) * S + s0 + sc4;
  short8 v0, v1;
#pragma unroll
  for (int j = 0; j < 8; ++j) { v0[j] = (short)tile[sc4 + j][dl]; v1[j] = (short)tile[sc4 + 8 + j][dl]; }
  *(short8*)dstp = v0;
  *(short8*)(dstp + 8) = v1;
}

__global__ void fill_k(float* __restrict__ o, int n, float v)
{
  int i = blockIdx.x * 256 + threadIdx.x;
  if (i < n) o[i] = v;
}

// x[b,t,:] = bf16( 2*emb[tok] + pos[b] )   (reference quirk: pos indexed by BATCH b)
__global__ void embed_k(const int* __restrict__ tok, const float* __restrict__ emb,
                        u16* __restrict__ X)
{
  const long idx = (long)blockIdx.x * 256 + threadIdx.x;
  const int d = (int)(idx & (CD - 1));
  const int m = (int)(idx >> 9);
  const int b = m >> 8;
  const float e = emb[(long)tok[m] * CD + d];
  const int i2 = d >> 1;
  const float den = __expf(-(float)(2 * i2) * (9.210340371976184f / 512.f));
  const float ang = (float)b * den;
  const float p = (d & 1) ? __cosf(ang) : __sinf(ang);
  X[idx] = f2bf(2.f * e + p);
}

// O = LN(X + Y) * g + b ; one block per row, D=512, f32 stats
__global__ void ln_res_k(const u16* __restrict__ X, const u16* __restrict__ Y,
                         const float* __restrict__ g, const float* __restrict__ bta,
                         u16* __restrict__ O)
{
  const int m = blockIdx.x, t = threadIdx.x;
  const long base = (long)m * CD;
  float v0 = bf2f(X[base + t]) + bf2f(Y[base + t]);
  float v1 = bf2f(X[base + t + 256]) + bf2f(Y[base + t + 256]);
  __shared__ float red[256];
  red[t] = v0 + v1; __syncthreads();
  for (int s = 128; s > 0; s >>= 1) { if (t < s) red[t] += red[t + s]; __syncthreads(); }
  const float mean = red[0] * (1.f / 512.f);
  __syncthreads();
  const float d0 = v0 - mean, d1 = v1 - mean;
  red[t] = d0 * d0 + d1 * d1; __syncthreads();
  for (int s = 128; s > 0; s >>= 1) { if (t < s) red[t] += red[t + s]; __syncthreads(); }
  const float rstd = rsqrtf(red[0] * (1.f / 512.f) + 1e-5f);
  O[base + t]       = f2bf(d0 * rstd * g[t] + bta[t]);
  O[base + t + 256] = f2bf(d1 * rstd * g[t + 256] + bta[t + 256]);
}

__global__ void cumsum_k(const int* __restrict__ dur, int* __restrict__ cums)
{
  int b = threadIdx.x;
  if (b < CB) {
    int s = 0;
    for (int t = 0; t < CT; ++t) { s += dur[b * CT + t]; cums[b * CT + t] = s; }
  }
}

__global__ void regulate_k(const u16* __restrict__ xe, const int* __restrict__ cums,
                           const int* __restrict__ mlen, u16* __restrict__ xd)
{
  const int m = blockIdx.x;
  const int b = m >> 10, f = m & (CMEL - 1);
  int lo = 0, hi = CT;
  while (lo < hi) { int mid = (lo + hi) >> 1; if (cums[b * CT + mid] <= f) lo = mid + 1; else hi = mid; }
  const int idx = min(lo, CT - 1);
  const bool keep = (f <= mlen[b]);
  const u16* src = xe + ((long)b * CT + idx) * CD;
  u16* dst = xd + (long)m * CD;
  const int t = threadIdx.x;
  dst[t]       = keep ? src[t] : (u16)0;
  dst[t + 256] = keep ? src[t + 256] : (u16)0;
}

// ---------------------------------------------------------------------------
extern "C" void kernel_launch(void* const* d_in, const int* in_sizes, int n_in,
                              void* d_out, int out_size, void* d_ws, size_t ws_size,
                              hipStream_t stream)
{
  (void)in_sizes; (void)n_in;
  const int*   tokens = (const int*)d_in[0];
  const int*   tlen   = (const int*)d_in[1];
  const int*   mlen   = (const int*)d_in[2];
  const int*   dur    = (const int*)d_in[3];
  const float* emb    = (const float*)d_in[5];
  const float* ew[12]; const float* dw[12];
  for (int i = 0; i < 12; ++i) { ew[i] = (const float*)d_in[6 + i]; dw[i] = (const float*)d_in[18 + i]; }
  const float* out_w = (const float*)d_in[30];
  const float* out_b = (const float*)d_in[31];

  const int Me = CB * CT;       // 4096
  const int Md = CB * CMEL;     // 16384

  const size_t SZ_ZP   = 256;
  const size_t SZ_WBUF = (size_t)3 * CD * CINTER * 2;
  const size_t SZ_XE   = (size_t)Me * CD * 2;
  const size_t SZ_XD   = (size_t)Md * CD * 2;     // x, x1(ctx), yb(vt)
  const size_t SZ_QKV  = (size_t)Md * CQKV * 2;   // 50.3 MB
  const size_t SZ_HB   = (size_t)Md * CINTER * 2; // 67.1 MB
  const size_t SZ_CUMS = (size_t)CB * CT * 4;
  auto al = [](size_t b) { return (b + 255) & ~(size_t)255; };
  size_t U = al(SZ_QKV) > al(SZ_HB) ? al(SZ_QKV) : al(SZ_HB);
  size_t total = al(SZ_ZP) + al(SZ_WBUF) + al(SZ_XE) + 3 * al(SZ_XD) + U + al(SZ_CUMS);
  if (total > ws_size) {
    fill_k<<<dim3((unsigned)((out_size + 255) / 256)), dim3(256), 0, stream>>>(
        (float*)d_out, out_size, 1000.0f);
    return;
  }

  char* p = (char*)d_ws;
  auto take = [&](size_t bytes) { char* r = p; p += al(bytes); return r; };
  u16*  zp   = (u16*)take(SZ_ZP);
  u16*  wbuf = (u16*)take(SZ_WBUF);
  u16*  xe   = (u16*)take(SZ_XE);
  u16*  xd   = (u16*)take(SZ_XD);
  u16*  x1   = (u16*)take(SZ_XD);   // also ctx during attention
  u16*  yb   = (u16*)take(SZ_XD);   // also vt during attention
  char* U0   = take(U);
  u16*  qkvB = (u16*)U0;
  u16*  hb   = (u16*)U0;
  int* cums = (int*)take(SZ_CUMS);

  hipMemsetAsync(zp, 0, SZ_ZP, stream);

  auto cvtT = [&](const float* s, u16* d, int K, int N, int taps) {
    cvt_t_k<<<dim3((unsigned)((N + 31) / 32), (unsigned)((K + 31) / 32), (unsigned)taps),
              dim3(256), 0, stream>>>(s, d, K, N);
  };

  embed_k<<<dim3((unsigned)((long)Me * CD / 256)), dim3(256), 0, stream>>>(tokens, emb, xe);

  auto run_stack = [&](u16* x, int S, int M, const int* lens, const float* const* W) {
    u16* vt = yb;
    for (int l = 0; l < CL; ++l) {
      // qkv = x @ Wqkv + b
      cvtT(W[0] + (long)l * CD * CQKV, wbuf, CD, CQKV, 1);
      gemm2_k<1, false><<<dim3(CQKV / 128, M / 128), dim3(256), 0, stream>>>(
          x, wbuf, qkvB, W[1] + l * CQKV, M, CQKV, CD, CD, CD, CQKV, S - 1, 0, zp);
      // V^T
      vtr_k<<<dim3((unsigned)(S / 64), (unsigned)(CB * CH)), dim3(256), 0, stream>>>(qkvB, vt, S);
      // fused attention -> ctx (= x1)
      attn_k<<<dim3((unsigned)(S / 128), (unsigned)(CB * CH)), dim3(512), 0, stream>>>(
          qkvB, vt, x1, lens, S);
      // proj: ctx @ Wo + bo -> yb
      cvtT(W[2] + (long)l * CD * CD, wbuf, CD, CD, 1);
      gemm2_k<1, false><<<dim3(CD / 128, M / 128), dim3(256), 0, stream>>>(
          x1, wbuf, yb, W[3] + l * CD, M, CD, CD, CD, CD, CD, S - 1, 0, zp);
      ln_res_k<<<dim3((unsigned)M), dim3(256), 0, stream>>>(x, yb, W[4] + l * CD, W[5] + l * CD, x1);
      // conv1 (3-tap) + relu
      cvtT(W[6] + (long)l * 3 * CD * CINTER, wbuf, CD, CINTER, 3);
      gemm2_k<3, true><<<dim3(CINTER / 128, M / 128), dim3(256), 0, stream>>>(
          x1, wbuf, hb, W[7] + l * CINTER, M, CINTER, CD, CD, CD, CINTER,
          S - 1, (long)CD * CINTER, zp);
      // conv2 (3-tap)
      cvtT(W[8] + (long)l * 3 * CINTER * CD, wbuf, CINTER, CD, 3);
      gemm2_k<3, false><<<dim3(CD / 128, M / 128), dim3(256), 0, stream>>>(
          hb, wbuf, yb, W[9] + l * CD, M, CD, CINTER, CINTER, CINTER, CD,
          S - 1, (long)CINTER * CD, zp);
      ln_res_k<<<dim3((unsigned)M), dim3(256), 0, stream>>>(x1, yb, W[10] + l * CD, W[11] + l * CD, x);
    }
  };

  run_stack(xe, CT, Me, tlen, ew);

  cumsum_k<<<dim3(1), dim3(64), 0, stream>>>(dur, cums);
  regulate_k<<<dim3((unsigned)(CB * CMEL)), dim3(256), 0, stream>>>(xe, cums, mlen, xd);

  run_stack(xd, CMEL, Md, mlen, dw);

  // final projection, transposed f32 store straight to d_out
  cvtT(out_w, wbuf, CD, COUT, 1);
  gemmF_k<128, 128><<<dim3(1, Md / 128), dim3(256), 0, stream>>>(
      xd, wbuf, (float*)d_out, out_b, Md, COUT, CD, CD, CD, zp);
}